// Round 16
// baseline (703.248 us; speedup 1.0000x reference)
//
#include <hip/hip_runtime.h>
#include <hip/hip_fp16.h>
#include <math.h>

constexpr int NN   = 20000;
constexpr int EE   = 320000;
constexpr int ET   = EE + NN;    // real edges with self loops
constexpr int ETP  = 840000;     // padded-slot capacity (>= sum pdeg)
constexpr int GG   = 128;
constexpr int DEE  = 64;
constexpr int DD   = 512;
constexpr int OUTD = 256;

using half8 = __attribute__((ext_vector_type(8))) _Float16;
using f32x4 = __attribute__((ext_vector_type(4))) float;

// ---- async global->LDS 16B (wave-uniform LDS base + lane*16 implicit) ----
__device__ __forceinline__ void ldg2lds16(const void* g, void* l) {
  __builtin_amdgcn_global_load_lds((const __attribute__((address_space(1))) unsigned*)g,
                                   (__attribute__((address_space(3))) unsigned*)l, 16, 0, 0);
}

// ---------------- embedding gather -> f16 ----------------
__global__ __launch_bounds__(256) void k_embf16(const int* __restrict__ ids,
                                                const float* __restrict__ emb,
                                                __half* __restrict__ x0) {
  for (int i = blockIdx.x * 256 + threadIdx.x; i < NN * 16; i += gridDim.x * 256) {
    int n = i >> 4, q = (i & 15) * 4;
    float4 v = *(const float4*)(emb + (size_t)ids[n] * DEE + q);
    __half2* o = (__half2*)(x0 + (size_t)n * DEE + q);
    o[0] = __floats2half2_rn(v.x, v.y);
    o[1] = __floats2half2_rn(v.z, v.w);
  }
}

// ---------------- weight transpose -> f16: T[n][k] = W[k][n] ----------------
__global__ __launch_bounds__(256) void k_wT16(const float* __restrict__ W,
                                              __half* __restrict__ Th,
                                              int K, int N) {
  __shared__ float t[32][33];
  int n0 = blockIdx.x * 32, k0 = blockIdx.y * 32;
  int c = threadIdx.x & 31, r4 = threadIdx.x >> 5;
  for (int rr = 0; rr < 32; rr += 8)
    t[rr + r4][c] = W[(size_t)(k0 + rr + r4) * N + n0 + c];
  __syncthreads();
  for (int rr = 0; rr < 32; rr += 8) {
    int n = n0 + rr + r4, k = k0 + c;
    Th[(size_t)n * K + k] = __float2half_rn(t[c][rr + r4]);
  }
}

// ---------------- CSR build (padded slots) ----------------
__global__ __launch_bounds__(256) void k_count(const int* __restrict__ ei, int* __restrict__ cnt) {
  for (int k = blockIdx.x * 256 + threadIdx.x; k < ET; k += gridDim.x * 256) {
    int d = (k < EE) ? ei[EE + k] : (k - EE);
    atomicAdd(&cnt[d], 1);
  }
}

__device__ __forceinline__ int pdegf(int c) {
  int p = (c + 3) & ~3;
  return (p < 20) ? 20 : p;
}

__global__ __launch_bounds__(1024) void k_scan(const int* __restrict__ cnt, int* __restrict__ off) {
  __shared__ int part[1024];
  int tid = threadIdx.x;
  constexpr int CH = (NN + 1023) / 1024;  // 20
  int base = tid * CH;
  int s = 0;
  for (int i = 0; i < CH; ++i) { int idx = base + i; if (idx < NN) s += pdegf(cnt[idx]); }
  part[tid] = s;
  __syncthreads();
  for (int o = 1; o < 1024; o <<= 1) {
    int add = (tid >= o) ? part[tid - o] : 0;
    int v = part[tid];
    __syncthreads();
    part[tid] = v + add;
    __syncthreads();
  }
  int run = (tid == 0) ? 0 : part[tid - 1];
  for (int i = 0; i < CH; ++i) {
    int idx = base + i;
    if (idx < NN) { off[idx] = run; run += pdegf(cnt[idx]); }
  }
  if (tid == 1023) off[NN] = run;
}

__global__ __launch_bounds__(256) void k_scatter(const int* __restrict__ ei, const int* __restrict__ off,
                                                 int* __restrict__ cur, int* __restrict__ csrc) {
  for (int k = blockIdx.x * 256 + threadIdx.x; k < ET; k += gridDim.x * 256) {
    int s = (k < EE) ? ei[k]      : (k - EE);
    int d = (k < EE) ? ei[EE + k] : (k - EE);
    int p = atomicAdd(&cur[d], 1);
    csrc[off[d] + p] = s;
  }
}

// ---------------- f16 MFMA GEMM (layers): C[M,NC] = A[M,K] @ B, f16 out ----------------
// Single-f16 B. DOTS=1: fused attention dots -> per-wc partials.
template<int DOTS>
__global__ __launch_bounds__(256) void k_mfma3(const __half* __restrict__ A,
                                               const __half* __restrict__ Bh,
                                               __half* __restrict__ C,
                                               int M, int K, int NC,
                                               const float* __restrict__ asw,
                                               const float* __restrict__ adw,
                                               float* __restrict__ sspS,
                                               float* __restrict__ sspD) {
  __shared__ __half lds[2 * 128 * 64];   // A | Bh, 16 KB each
  __half* As  = lds;
  __half* Bhs = lds + 8192;
  const int tid = threadIdx.x, l = tid & 63, w = tid >> 6;
  const int wr = w >> 1, wc = w & 1;
  const int m0 = blockIdx.y * 128, n0 = blockIdx.x * 128;
  const int l15 = l & 15, l16 = l >> 4;
  const int sr = l >> 3;
  const int ss = (l & 7) ^ sr;

  float a_s[4], a_d[4];
  if (DOTS) {
#pragma unroll
    for (int j = 0; j < 4; ++j) {
      int col = n0 + wc * 64 + j * 16 + l15;   // flat [H*C] index
      a_s[j] = asw[col];
      a_d[j] = adw[col];
    }
  }

  f32x4 acc[4][4] = {};
  for (int k0 = 0; k0 < K; k0 += 64) {
#pragma unroll
    for (int j = 0; j < 4; ++j) {
      int rbase = j * 32 + w * 8;
      int rl = rbase + sr;
      int gA = min(m0 + rl, M - 1);
      int gB = n0 + rl;
      const size_t ko = (size_t)(k0 + ss * 8);
      ldg2lds16(A  + (size_t)gA * K + ko, As  + rbase * 64);
      ldg2lds16(Bh + (size_t)gB * K + ko, Bhs + rbase * 64);
    }
    __syncthreads();
#pragma unroll
    for (int kh = 0; kh < 2; ++kh) {
      half8 af[4], bhf[4];
#pragma unroll
      for (int t = 0; t < 4; ++t) {
        int ra = wr * 64 + t * 16 + l15;
        int ca = (kh * 4 + l16) ^ (ra & 7);
        af[t] = *(const half8*)(As + ra * 64 + ca * 8);
        int rb = wc * 64 + t * 16 + l15;
        int cb = (kh * 4 + l16) ^ (rb & 7);
        bhf[t] = *(const half8*)(Bhs + rb * 64 + cb * 8);
      }
#pragma unroll
      for (int i = 0; i < 4; ++i)
#pragma unroll
        for (int j = 0; j < 4; ++j)
          acc[i][j] = __builtin_amdgcn_mfma_f32_16x16x32_f16(af[i], bhf[j], acc[i][j], 0, 0, 0);
    }
    __syncthreads();
  }
  const int hh = n0 >> 7;   // head of this col-block (NC=512)
#pragma unroll
  for (int i = 0; i < 4; ++i) {
#pragma unroll
    for (int r = 0; r < 4; ++r) {
      int row = m0 + wr * 64 + i * 16 + l16 * 4 + r;
      if (DOTS) {
        float vs = 0.f, vd = 0.f;
#pragma unroll
        for (int j = 0; j < 4; ++j) {
          vs = fmaf(acc[i][j][r], a_s[j], vs);
          vd = fmaf(acc[i][j][r], a_d[j], vd);
        }
#pragma unroll
        for (int o = 1; o < 16; o <<= 1) { vs += __shfl_xor(vs, o); vd += __shfl_xor(vd, o); }
        if (l15 == 0 && row < M) {
          sspS[(size_t)wc * (NN * 4) + row * 4 + hh] = vs;
          sspD[(size_t)wc * (NN * 4) + row * 4 + hh] = vd;
        }
      }
      if (row >= M) continue;
#pragma unroll
      for (int j = 0; j < 4; ++j) {
        int col = n0 + wc * 64 + j * 16 + l15;
        C[(size_t)row * NC + col] = __float2half(acc[i][j][r]);
      }
    }
  }
}

// ---------------- combine the two wc-partials into ssrc/sdst ----------------
__global__ __launch_bounds__(256) void k_scomb(const float* __restrict__ sspS,
                                               const float* __restrict__ sspD,
                                               float* __restrict__ ssrc,
                                               float* __restrict__ sdst) {
  int idx = blockIdx.x * 256 + threadIdx.x;
  if (idx < NN * 4) {
    ssrc[idx] = sspS[idx] + sspS[NN * 4 + idx];
    sdst[idx] = sspD[idx] + sspD[NN * 4 + idx];
  }
}

// ---------------- split-K MFMA partial GEMM (MLP head): part[kz][M][NC] f32 ----------------
__global__ __launch_bounds__(256) void k_mfmaK(const __half* __restrict__ A,
                                               const __half* __restrict__ Bh,
                                               float* __restrict__ part,
                                               int M, int K, int NC, int Kc) {
  __shared__ __half lds[2 * 128 * 64];
  __half* As  = lds;
  __half* Bhs = lds + 8192;
  const int tid = threadIdx.x, l = tid & 63, w = tid >> 6;
  const int wr = w >> 1, wc = w & 1;
  const int m0 = blockIdx.y * 128, n0 = blockIdx.x * 128;
  const int kz = blockIdx.z;
  const int kb = kz * Kc, ke = kb + Kc;
  const int l15 = l & 15, l16 = l >> 4;
  const int sr = l >> 3;
  const int ss = (l & 7) ^ sr;

  f32x4 acc[4][4] = {};
  for (int k0 = kb; k0 < ke; k0 += 64) {
#pragma unroll
    for (int j = 0; j < 4; ++j) {
      int rbase = j * 32 + w * 8;
      int rl = rbase + sr;
      int gA = min(m0 + rl, M - 1);
      int gB = n0 + rl;
      const size_t ko = (size_t)(k0 + ss * 8);
      ldg2lds16(A  + (size_t)gA * K + ko, As  + rbase * 64);
      ldg2lds16(Bh + (size_t)gB * K + ko, Bhs + rbase * 64);
    }
    __syncthreads();
#pragma unroll
    for (int kh = 0; kh < 2; ++kh) {
      half8 af[4], bhf[4];
#pragma unroll
      for (int t = 0; t < 4; ++t) {
        int ra = wr * 64 + t * 16 + l15;
        int ca = (kh * 4 + l16) ^ (ra & 7);
        af[t] = *(const half8*)(As + ra * 64 + ca * 8);
        int rb = wc * 64 + t * 16 + l15;
        int cb = (kh * 4 + l16) ^ (rb & 7);
        bhf[t] = *(const half8*)(Bhs + rb * 64 + cb * 8);
      }
#pragma unroll
      for (int i = 0; i < 4; ++i)
#pragma unroll
        for (int j = 0; j < 4; ++j)
          acc[i][j] = __builtin_amdgcn_mfma_f32_16x16x32_f16(af[i], bhf[j], acc[i][j], 0, 0, 0);
    }
    __syncthreads();
  }
  float* pz = part + (size_t)kz * M * NC;
#pragma unroll
  for (int i = 0; i < 4; ++i) {
#pragma unroll
    for (int r = 0; r < 4; ++r) {
      int row = m0 + wr * 64 + i * 16 + l16 * 4 + r;
      if (row >= M) continue;
#pragma unroll
      for (int j = 0; j < 4; ++j) {
        int col = n0 + wc * 64 + j * 16 + l15;
        pz[(size_t)row * NC + col] = acc[i][j][r];
      }
    }
  }
}

// ---------------- finalize p1: sum 8 partials + bias + GELU -> f16 ----------------
__global__ __launch_bounds__(256) void k_fin_gelu(const float* __restrict__ part,
                                                  const float* __restrict__ bias,
                                                  __half* __restrict__ outh) {
  int idx = blockIdx.x * 256 + threadIdx.x;   // [GG*1024)
  if (idx >= GG * 1024) return;
  int c = idx & 1023;
  float v = bias[c];
#pragma unroll
  for (int z = 0; z < 8; ++z) v += part[(size_t)z * GG * 1024 + idx];
  v = 0.5f * v * (1.0f + erff(v * 0.70710678118654752f));
  outh[idx] = __float2half_rn(v);
}

// ---------------- finalize p2 + row L2 normalize: one block per graph ----------------
__global__ __launch_bounds__(256) void k_fin_l2(const float* __restrict__ part,
                                                const float* __restrict__ bias,
                                                float* __restrict__ out) {
  int g = blockIdx.x, t = threadIdx.x;   // t < 256 = OUTD
  float v = bias[t];
#pragma unroll
  for (int z = 0; z < 8; ++z) v += part[(size_t)z * GG * OUTD + g * OUTD + t];
  float q = v * v;
#pragma unroll
  for (int o = 32; o; o >>= 1) q += __shfl_xor(q, o);
  __shared__ float w[4];
  int wv = t >> 6, ln = t & 63;
  if (ln == 0) w[wv] = q;
  __syncthreads();
  float tot = w[0] + w[1] + w[2] + w[3];
  float nrm = fmaxf(sqrtf(tot), 1e-12f);
  out[(size_t)g * OUTD + t] = v / nrm;
}

// ---------------- per-edge packed records: {src[15b] << 16 | f16(alpha)}; zero pads ----------------
__global__ __launch_bounds__(256) void k_eweight(const float* __restrict__ ssrc,
                                                 const float* __restrict__ sdst,
                                                 const int* __restrict__ poff,
                                                 const int* __restrict__ cnt_,
                                                 const int* __restrict__ csr,
                                                 unsigned* __restrict__ ewk) {
  int wv = threadIdx.x >> 6, ln = threadIdx.x & 63;
  int n = blockIdx.x * 4 + wv;
  int beg = poff[n], pend = poff[n + 1];
  int deg = cnt_[n];
  float4 sd4 = *(const float4*)(sdst + (size_t)n * 4);
  float4 wreg[2];
  int    skreg[2];
  float d0 = 0.f, d1 = 0.f, d2 = 0.f, d3 = 0.f;
  int cnt = 0;
  for (int j = ln; j < deg; j += 64) {
    int sk = csr[beg + j];
    float4 s = *(const float4*)(ssrc + (size_t)sk * 4);
    float e0 = s.x + sd4.x; e0 = (e0 > 0.f) ? e0 : 0.2f * e0;
    float e1 = s.y + sd4.y; e1 = (e1 > 0.f) ? e1 : 0.2f * e1;
    float e2 = s.z + sd4.z; e2 = (e2 > 0.f) ? e2 : 0.2f * e2;
    float e3 = s.w + sd4.w; e3 = (e3 > 0.f) ? e3 : 0.2f * e3;
    float4 wv4 = make_float4(__expf(e0), __expf(e1), __expf(e2), __expf(e3));
    if (cnt < 2) { wreg[cnt] = wv4; skreg[cnt] = sk; }
    ++cnt;
    d0 += wv4.x; d1 += wv4.y; d2 += wv4.z; d3 += wv4.w;
  }
#pragma unroll
  for (int o = 32; o; o >>= 1) {
    d0 += __shfl_xor(d0, o); d1 += __shfl_xor(d1, o);
    d2 += __shfl_xor(d2, o); d3 += __shfl_xor(d3, o);
  }
  float r0 = 1.0f / d0, r1 = 1.0f / d1, r2 = 1.0f / d2, r3 = 1.0f / d3;
  cnt = 0;
  int plen = pend - beg;
  for (int j = ln; j < plen; j += 64) {
    int k = beg + j;
    if (j < deg) {
      float4 wv4;
      int sk;
      if (cnt < 2) { wv4 = wreg[cnt]; sk = skreg[cnt]; }
      else {
        sk = csr[k];
        float4 s = *(const float4*)(ssrc + (size_t)sk * 4);
        float e0 = s.x + sd4.x; e0 = (e0 > 0.f) ? e0 : 0.2f * e0;
        float e1 = s.y + sd4.y; e1 = (e1 > 0.f) ? e1 : 0.2f * e1;
        float e2 = s.z + sd4.z; e2 = (e2 > 0.f) ? e2 : 0.2f * e2;
        float e3 = s.w + sd4.w; e3 = (e3 > 0.f) ? e3 : 0.2f * e3;
        wv4 = make_float4(__expf(e0), __expf(e1), __expf(e2), __expf(e3));
      }
      ++cnt;
      unsigned sh = (unsigned)sk << 16;
      ewk[k]           = sh | (unsigned)__half_as_ushort(__float2half_rn(wv4.x * r0));
      ewk[ETP + k]     = sh | (unsigned)__half_as_ushort(__float2half_rn(wv4.y * r1));
      ewk[2 * ETP + k] = sh | (unsigned)__half_as_ushort(__float2half_rn(wv4.z * r2));
      ewk[3 * ETP + k] = sh | (unsigned)__half_as_ushort(__float2half_rn(wv4.w * r3));
    } else {
      ewk[k]           = 0u;
      ewk[ETP + k]     = 0u;
      ewk[2 * ETP + k] = 0u;
      ewk[3 * ETP + k] = 0u;
    }
  }
}

// ---------------- channel-split aggregation: padded slots, zero masking ----------------
// cb = blockIdx % 8 pins a 64-ch slice to one XCD's L2. Lane l = (g=l>>4 edge-group, q=l&15 ch-quad).
// Slots are pre-padded (>=20, 4-aligned) with zero-alpha records -> unconditional loads/fma.
__device__ __forceinline__ void acc4mix(float* acc, unsigned rec, const uint2& x) {
  asm("v_fma_mix_f32 %0, %1, %2, %0 op_sel:[0,0,0] op_sel_hi:[1,1,0]" : "+v"(acc[0]) : "v"(rec), "v"(x.x));
  asm("v_fma_mix_f32 %0, %1, %2, %0 op_sel:[0,1,0] op_sel_hi:[1,1,0]" : "+v"(acc[1]) : "v"(rec), "v"(x.x));
  asm("v_fma_mix_f32 %0, %1, %2, %0 op_sel:[0,0,0] op_sel_hi:[1,1,0]" : "+v"(acc[2]) : "v"(rec), "v"(x.y));
  asm("v_fma_mix_f32 %0, %1, %2, %0 op_sel:[0,1,0] op_sel_hi:[1,1,0]" : "+v"(acc[3]) : "v"(rec), "v"(x.y));
}

__global__ __launch_bounds__(256, 8) void k_aggc(const __half* __restrict__ xp16,
                                                 const unsigned* __restrict__ ewk,
                                                 const int* __restrict__ poff,
                                                 const float* __restrict__ bias,
                                                 __half* __restrict__ xio) {  // in: residual f16, out: pre-LN f16
  const int bid = blockIdx.x;
  const int cb = bid & 7;
  const int chunk = bid >> 3;
  const int wv = threadIdx.x >> 6, l = threadIdx.x & 63;
  const int g = l >> 4, q = l & 15;
  const int h = cb >> 1;
  const int n = __builtin_amdgcn_readfirstlane(chunk * 4 + wv);
  const int beg = poff[n], pend = poff[n + 1];
  const unsigned* __restrict__ ewh = ewk + (size_t)h * ETP;
  const __half* __restrict__ xb = xp16 + cb * 64;     // wave-uniform base
  const unsigned qoff = (unsigned)q * 8;              // byte offset of channel quad

  // independent prefetches
  uint2 rres = *(const uint2*)(xio + (size_t)n * DD + cb * 64 + q * 4);
  float4 bi = *(const float4*)(bias + cb * 64 + q * 4);

  float acc[4] = {};
  {
    // ---- 5-group block, unconditional (slots always >= 20) ----
    unsigned r[5];
    uint2 x[5];
#pragma unroll
    for (int i = 0; i < 5; ++i) r[i] = ewh[beg + i * 4 + g];
#pragma unroll
    for (int i = 0; i < 5; ++i)
      x[i] = *(const uint2*)((const char*)xb + (((r[i] >> 6) & 0xFFFFFC00u) | qoff));
#pragma unroll
    for (int i = 0; i < 5; ++i) acc4mix(acc, r[i], x[i]);
  }
  // ---- tail (pdeg > 20), unconditional 4-steps ----
  for (int k = beg + 20; k < pend; k += 4) {
    unsigned rr = ewh[k + g];
    uint2 xx = *(const uint2*)((const char*)xb + (((rr >> 6) & 0xFFFFFC00u) | qoff));
    acc4mix(acc, rr, xx);
  }
  // reduce over the 4 edge-groups (strides 16, 32)
#pragma unroll
  for (int j = 0; j < 4; ++j) {
    acc[j] += __shfl_xor(acc[j], 16);
    acc[j] += __shfl_xor(acc[j], 32);
  }
  if (g == 0) {
    float2 fr0 = __half22float2(*(__half2*)&rres.x);
    float2 fr1 = __half22float2(*(__half2*)&rres.y);
    float o0 = acc[0] + bi.x + fr0.x;
    float o1 = acc[1] + bi.y + fr0.y;
    float o2 = acc[2] + bi.z + fr1.x;
    float o3 = acc[3] + bi.w + fr1.y;
    uint2 st;
    *(__half2*)&st.x = __floats2half2_rn(o0, o1);
    *(__half2*)&st.y = __floats2half2_rn(o2, o3);
    *(uint2*)(xio + (size_t)n * DD + cb * 64 + q * 4) = st;
  }
}

// ---------------- per-graph LN stats directly from f16 xio (batch sorted) ----------------
__device__ __forceinline__ int lowb(const int* a, int n, int key) {
  int lo = 0, hi = n;
  while (lo < hi) { int mid = (lo + hi) >> 1; if (a[mid] < key) lo = mid + 1; else hi = mid; }
  return lo;
}

__global__ __launch_bounds__(256) void k_stats2(const __half* __restrict__ xio,
                                                const int* __restrict__ batch,
                                                float* __restrict__ gmu, float* __restrict__ grstd) {
  int g = blockIdx.x, tid = threadIdx.x;
  __shared__ int sb, se;
  __shared__ float rs[4], rq[4];
  if (tid == 0) { sb = lowb(batch, NN, g); se = lowb(batch, NN, g + 1); }
  __syncthreads();
  int b = sb, e = se;
  const __half* base = xio + (size_t)b * DD;
  int n8 = (e - b) * DD / 8;
  float ps = 0.f, pq = 0.f;
  for (int i8 = tid; i8 < n8; i8 += 256) {
    uint4 raw = *(const uint4*)(base + (size_t)i8 * 8);
    const __half2* hp = (const __half2*)&raw;
#pragma unroll
    for (int j = 0; j < 4; ++j) {
      float2 f = __half22float2(hp[j]);
      ps += f.x + f.y;
      pq += f.x * f.x + f.y * f.y;
    }
  }
#pragma unroll
  for (int o = 32; o; o >>= 1) { ps += __shfl_xor(ps, o); pq += __shfl_xor(pq, o); }
  int wv = tid >> 6, ln = tid & 63;
  if (ln == 0) { rs[wv] = ps; rq[wv] = pq; }
  __syncthreads();
  if (tid == 0) {
    float S = rs[0] + rs[1] + rs[2] + rs[3];
    float Q = rq[0] + rq[1] + rq[2] + rq[3];
    float cnt = fmaxf((float)(e - b) * (float)DD, 1.0f);
    float mu  = S / cnt;
    float var = fmaxf(Q / cnt - mu * mu, 0.0f);
    gmu[g]   = mu;
    grstd[g] = rsqrtf(var + 1e-5f);
  }
}

// ---------------- graph-LN normalize, f16 in / f16 out ----------------
__global__ __launch_bounds__(256) void k_norm(__half* __restrict__ x, const int* __restrict__ batch,
                                              const float* __restrict__ gmu, const float* __restrict__ grstd,
                                              const float* __restrict__ lnw, const float* __restrict__ lnb) {
  for (int i8 = blockIdx.x * 256 + threadIdx.x; i8 < NN * DD / 8; i8 += gridDim.x * 256) {
    int i = i8 * 8;
    int n = i >> 9, d = i & 511;
    int g = batch[n];
    float mu = gmu[g], rs = grstd[g];
    uint4 raw = *(uint4*)(x + i);
    __half2* hp = (__half2*)&raw;
    float4 w0 = *(const float4*)(lnw + d);
    float4 w1 = *(const float4*)(lnw + d + 4);
    float4 b0 = *(const float4*)(lnb + d);
    float4 b1 = *(const float4*)(lnb + d + 4);
    float wv[8] = {w0.x,w0.y,w0.z,w0.w,w1.x,w1.y,w1.z,w1.w};
    float bv[8] = {b0.x,b0.y,b0.z,b0.w,b1.x,b1.y,b1.z,b1.w};
#pragma unroll
    for (int j = 0; j < 4; ++j) {
      float2 f = __half22float2(hp[j]);
      f.x = (f.x - mu) * rs * wv[2*j]   + bv[2*j];
      f.y = (f.y - mu) * rs * wv[2*j+1] + bv[2*j+1];
      hp[j] = __floats2half2_rn(f.x, f.y);
    }
    *(uint4*)(x + i) = raw;
  }
}

// ---------------- pooling: mean + max per graph -> f16 [G][1024] ----------------
__global__ __launch_bounds__(256) void k_pool(const __half* __restrict__ x, const int* __restrict__ batch,
                                              __half* __restrict__ pool16) {
  int g = blockIdx.x, tid = threadIdx.x;
  __shared__ int sb, se;
  if (tid == 0) { sb = lowb(batch, NN, g); se = lowb(batch, NN, g + 1); }
  __syncthreads();
  int b = sb, e = se;
  float s0 = 0.f, s1 = 0.f, m0 = -INFINITY, m1 = -INFINITY;
  for (int n = b; n < e; ++n) {
    float v0 = __half2float(x[(size_t)n * DD + tid]);
    float v1 = __half2float(x[(size_t)n * DD + tid + 256]);
    s0 += v0; s1 += v1;
    m0 = fmaxf(m0, v0); m1 = fmaxf(m1, v1);
  }
  int cnt = e - b;
  float inv = 1.0f / (float)(cnt > 0 ? cnt : 1);
  pool16[(size_t)g * 1024 + tid]             = __float2half_rn(s0 * inv);
  pool16[(size_t)g * 1024 + tid + 256]       = __float2half_rn(s1 * inv);
  pool16[(size_t)g * 1024 + 512 + tid]       = __float2half_rn((cnt > 0) ? m0 : 0.f);
  pool16[(size_t)g * 1024 + 512 + tid + 256] = __float2half_rn((cnt > 0) ? m1 : 0.f);
}

// ---------------- launcher ----------------
extern "C" void kernel_launch(void* const* d_in, const int* in_sizes, int n_in,
                              void* d_out, int out_size, void* d_ws, size_t ws_size,
                              hipStream_t stream) {
  const int*   node_ids = (const int*)d_in[0];
  const int*   ei       = (const int*)d_in[1];
  const int*   batch    = (const int*)d_in[2];
  const float* emb      = (const float*)d_in[3];
  const float* W[4]  = {(const float*)d_in[4],  (const float*)d_in[10], (const float*)d_in[16], (const float*)d_in[22]};
  const float* AS[4] = {(const float*)d_in[5],  (const float*)d_in[11], (const float*)d_in[17], (const float*)d_in[23]};
  const float* AD[4] = {(const float*)d_in[6],  (const float*)d_in[12], (const float*)d_in[18], (const float*)d_in[24]};
  const float* BV[4] = {(const float*)d_in[7],  (const float*)d_in[13], (const float*)d_in[19], (const float*)d_in[25]};
  const float* LW[4] = {(const float*)d_in[8],  (const float*)d_in[14], (const float*)d_in[20], (const float*)d_in[26]};
  const float* LB[4] = {(const float*)d_in[9],  (const float*)d_in[15], (const float*)d_in[21], (const float*)d_in[27]};
  const float* res_w0 = (const float*)d_in[28];
  const float* p1w    = (const float*)d_in[29];
  const float* p1b    = (const float*)d_in[30];
  const float* p2w    = (const float*)d_in[31];
  const float* p2b    = (const float*)d_in[32];
  float* out = (float*)d_out;

  char* ws = (char*)d_ws;
  size_t pos = 0;
  auto alloc = [&](size_t bytes) -> char* {
    char* p = ws + pos;
    pos = (pos + bytes + 255) & ~size_t(255);
    return p;
  };
  __half* xr16  = (__half*)alloc((size_t)NN * DD * 2);   // unified residual / GEMM-A / pool input
  __half* xp16  = (__half*)alloc((size_t)NN * DD * 2);
  __half* x0f   = (__half*)alloc((size_t)NN * DEE * 2);
  float*  ssrc  = (float*)alloc((size_t)NN * 4 * 4);
  float*  sdst  = (float*)alloc((size_t)NN * 4 * 4);
  float*  sspS  = (float*)alloc((size_t)2 * NN * 4 * 4);
  float*  sspD  = (float*)alloc((size_t)2 * NN * 4 * 4);
  int*    poff  = (int*)alloc((size_t)(NN + 1) * 4);
  int*    cntb  = (int*)alloc((size_t)NN * 4);
  int*    ccur  = (int*)alloc((size_t)NN * 4);
  int*    csrc  = (int*)alloc((size_t)ETP * 4);
  unsigned* ewk = (unsigned*)alloc((size_t)ETP * 4 * 4); // 4 head planes of packed {src,f16 alpha}
  float*  gmu   = (float*)alloc((size_t)GG * 4 * 2);
  float*  grstd = gmu + GG;
  // transposed f16 weights
  __half* w0t = (__half*)alloc((size_t)DEE * DD * 2);
  __half* rwt = (__half*)alloc((size_t)DEE * DD * 2);
  __half* wt[4] = {w0t, nullptr, nullptr, nullptr};
  for (int i = 1; i < 4; ++i) wt[i] = (__half*)alloc((size_t)DD * DD * 2);
  __half* p1t = (__half*)alloc((size_t)1024 * 1024 * 2);
  __half* p2t = (__half*)alloc((size_t)OUTD * 1024 * 2);
  __half* pool16 = (__half*)alloc((size_t)GG * 1024 * 2);
  __half* h1_16  = (__half*)alloc((size_t)GG * 1024 * 2);
  float*  part1  = (float*)alloc((size_t)8 * GG * 1024 * 4);  // 4 MB
  float*  part2  = (float*)alloc((size_t)8 * GG * OUTD * 4);  // 1 MB
  (void)ws_size; (void)in_sizes; (void)n_in; (void)out_size;

  // ---- CSR (padded) + weight prep ----
  hipMemsetAsync(cntb, 0, (size_t)NN * 4, stream);
  hipMemsetAsync(ccur, 0, (size_t)NN * 4, stream);
  k_embf16<<<1250, 256, 0, stream>>>(node_ids, emb, x0f);
  k_count<<<1024, 256, 0, stream>>>(ei, cntb);
  k_scan<<<1, 1024, 0, stream>>>(cntb, poff);
  k_scatter<<<1024, 256, 0, stream>>>(ei, poff, ccur, csrc);
  k_wT16<<<dim3(16, 2),  256, 0, stream>>>(W[0],   w0t, DEE, DD);
  k_wT16<<<dim3(16, 2),  256, 0, stream>>>(res_w0, rwt, DEE, DD);
  for (int i = 1; i < 4; ++i)
    k_wT16<<<dim3(16, 16), 256, 0, stream>>>(W[i], wt[i], DD, DD);
  k_wT16<<<dim3(32, 32), 256, 0, stream>>>(p1w, p1t, 1024, 1024);
  k_wT16<<<dim3(8, 32),  256, 0, stream>>>(p2w, p2t, 1024, OUTD);

  // ---- L0 projections (xp GEMM carries fused attention dots via wc-partials) ----
  k_mfma3<1><<<dim3(4, 157), 256, 0, stream>>>(x0f, w0t, xp16, NN, DEE, DD,
                                               AS[0], AD[0], sspS, sspD);
  k_mfma3<0><<<dim3(4, 157), 256, 0, stream>>>(x0f, rwt, xr16, NN, DEE, DD,
                                               nullptr, nullptr, nullptr, nullptr);
  k_scomb<<<(NN * 4 + 255) / 256, 256, 0, stream>>>(sspS, sspD, ssrc, sdst);

  // ---- 4 GAT layers ----
  for (int L = 0; L < 4; ++L) {
    k_eweight<<<NN / 4, 256, 0, stream>>>(ssrc, sdst, poff, cntb, csrc, ewk);
    k_aggc<<<NN * 2, 256, 0, stream>>>(xp16, ewk, poff, BV[L], xr16);
    k_stats2<<<GG, 256, 0, stream>>>(xr16, batch, gmu, grstd);
    k_norm<<<2048, 256, 0, stream>>>(xr16, batch, gmu, grstd, LW[L], LB[L]);
    if (L < 3) {
      k_mfma3<1><<<dim3(4, 157), 256, 0, stream>>>(xr16, wt[L + 1], xp16, NN, DD, DD,
                                                   AS[L + 1], AD[L + 1], sspS, sspD);
      k_scomb<<<(NN * 4 + 255) / 256, 256, 0, stream>>>(sspS, sspD, ssrc, sdst);
    }
  }

  // ---- pool + MLP head (split-K) + fused finalize/normalize ----
  k_pool<<<GG, 256, 0, stream>>>(xr16, batch, pool16);
  k_mfmaK<<<dim3(8, 1, 8), 256, 0, stream>>>(pool16, p1t, part1, GG, 1024, 1024, 128);
  k_fin_gelu<<<512, 256, 0, stream>>>(part1, p1b, h1_16);
  k_mfmaK<<<dim3(2, 1, 8), 256, 0, stream>>>(h1_16, p2t, part2, GG, 1024, OUTD, 128);
  k_fin_l2<<<GG, 256, 0, stream>>>(part2, p2b, out);
}

// Round 17
// 636.743 us; speedup vs baseline: 1.1044x; 1.1044x over previous
//
#include <hip/hip_runtime.h>
#include <hip/hip_fp16.h>
#include <math.h>

constexpr int NN   = 20000;
constexpr int EE   = 320000;
constexpr int ET   = EE + NN;    // real edges with self loops
constexpr int ETP  = 840000;     // padded-slot capacity (>= sum pdeg)
constexpr int GG   = 128;
constexpr int DEE  = 64;
constexpr int DD   = 512;
constexpr int OUTD = 256;

using half8 = __attribute__((ext_vector_type(8))) _Float16;
using f32x4 = __attribute__((ext_vector_type(4))) float;

// ---- async global->LDS 16B (wave-uniform LDS base + lane*16 implicit) ----
__device__ __forceinline__ void ldg2lds16(const void* g, void* l) {
  __builtin_amdgcn_global_load_lds((const __attribute__((address_space(1))) unsigned*)g,
                                   (__attribute__((address_space(3))) unsigned*)l, 16, 0, 0);
}

// ---------------- embedding gather -> f16 ----------------
__global__ __launch_bounds__(256) void k_embf16(const int* __restrict__ ids,
                                                const float* __restrict__ emb,
                                                __half* __restrict__ x0) {
  for (int i = blockIdx.x * 256 + threadIdx.x; i < NN * 16; i += gridDim.x * 256) {
    int n = i >> 4, q = (i & 15) * 4;
    float4 v = *(const float4*)(emb + (size_t)ids[n] * DEE + q);
    __half2* o = (__half2*)(x0 + (size_t)n * DEE + q);
    o[0] = __floats2half2_rn(v.x, v.y);
    o[1] = __floats2half2_rn(v.z, v.w);
  }
}

// ---------------- weight transpose -> f16: T[n][k] = W[k][n] ----------------
__global__ __launch_bounds__(256) void k_wT16(const float* __restrict__ W,
                                              __half* __restrict__ Th,
                                              int K, int N) {
  __shared__ float t[32][33];
  int n0 = blockIdx.x * 32, k0 = blockIdx.y * 32;
  int c = threadIdx.x & 31, r4 = threadIdx.x >> 5;
  for (int rr = 0; rr < 32; rr += 8)
    t[rr + r4][c] = W[(size_t)(k0 + rr + r4) * N + n0 + c];
  __syncthreads();
  for (int rr = 0; rr < 32; rr += 8) {
    int n = n0 + rr + r4, k = k0 + c;
    Th[(size_t)n * K + k] = __float2half_rn(t[c][rr + r4]);
  }
}

// ---------------- CSR build (padded slots) ----------------
__global__ __launch_bounds__(256) void k_count(const int* __restrict__ ei, int* __restrict__ cnt) {
  for (int k = blockIdx.x * 256 + threadIdx.x; k < ET; k += gridDim.x * 256) {
    int d = (k < EE) ? ei[EE + k] : (k - EE);
    atomicAdd(&cnt[d], 1);
  }
}

__device__ __forceinline__ int pdegf(int c) {
  int p = (c + 3) & ~3;
  return (p < 20) ? 20 : p;
}

__global__ __launch_bounds__(1024) void k_scan(const int* __restrict__ cnt, int* __restrict__ off) {
  __shared__ int part[1024];
  int tid = threadIdx.x;
  constexpr int CH = (NN + 1023) / 1024;  // 20
  int base = tid * CH;
  int s = 0;
  for (int i = 0; i < CH; ++i) { int idx = base + i; if (idx < NN) s += pdegf(cnt[idx]); }
  part[tid] = s;
  __syncthreads();
  for (int o = 1; o < 1024; o <<= 1) {
    int add = (tid >= o) ? part[tid - o] : 0;
    int v = part[tid];
    __syncthreads();
    part[tid] = v + add;
    __syncthreads();
  }
  int run = (tid == 0) ? 0 : part[tid - 1];
  for (int i = 0; i < CH; ++i) {
    int idx = base + i;
    if (idx < NN) { off[idx] = run; run += pdegf(cnt[idx]); }
  }
  if (tid == 1023) off[NN] = run;
}

__global__ __launch_bounds__(256) void k_scatter(const int* __restrict__ ei, const int* __restrict__ off,
                                                 int* __restrict__ cur, int* __restrict__ csrc) {
  for (int k = blockIdx.x * 256 + threadIdx.x; k < ET; k += gridDim.x * 256) {
    int s = (k < EE) ? ei[k]      : (k - EE);
    int d = (k < EE) ? ei[EE + k] : (k - EE);
    int p = atomicAdd(&cur[d], 1);
    csrc[off[d] + p] = s;
  }
}

// ---------------- f16 MFMA GEMM (layers): C[M,NC] = A[M,K] @ B, f16 out ----------------
// Single-f16 B. DOTS=1: fused attention dots -> per-wc partials.
template<int DOTS>
__global__ __launch_bounds__(256) void k_mfma3(const __half* __restrict__ A,
                                               const __half* __restrict__ Bh,
                                               __half* __restrict__ C,
                                               int M, int K, int NC,
                                               const float* __restrict__ asw,
                                               const float* __restrict__ adw,
                                               float* __restrict__ sspS,
                                               float* __restrict__ sspD) {
  __shared__ __half lds[2 * 128 * 64];   // A | Bh, 16 KB each
  __half* As  = lds;
  __half* Bhs = lds + 8192;
  const int tid = threadIdx.x, l = tid & 63, w = tid >> 6;
  const int wr = w >> 1, wc = w & 1;
  const int m0 = blockIdx.y * 128, n0 = blockIdx.x * 128;
  const int l15 = l & 15, l16 = l >> 4;
  const int sr = l >> 3;
  const int ss = (l & 7) ^ sr;

  float a_s[4], a_d[4];
  if (DOTS) {
#pragma unroll
    for (int j = 0; j < 4; ++j) {
      int col = n0 + wc * 64 + j * 16 + l15;   // flat [H*C] index
      a_s[j] = asw[col];
      a_d[j] = adw[col];
    }
  }

  f32x4 acc[4][4] = {};
  for (int k0 = 0; k0 < K; k0 += 64) {
#pragma unroll
    for (int j = 0; j < 4; ++j) {
      int rbase = j * 32 + w * 8;
      int rl = rbase + sr;
      int gA = min(m0 + rl, M - 1);
      int gB = n0 + rl;
      const size_t ko = (size_t)(k0 + ss * 8);
      ldg2lds16(A  + (size_t)gA * K + ko, As  + rbase * 64);
      ldg2lds16(Bh + (size_t)gB * K + ko, Bhs + rbase * 64);
    }
    __syncthreads();
#pragma unroll
    for (int kh = 0; kh < 2; ++kh) {
      half8 af[4], bhf[4];
#pragma unroll
      for (int t = 0; t < 4; ++t) {
        int ra = wr * 64 + t * 16 + l15;
        int ca = (kh * 4 + l16) ^ (ra & 7);
        af[t] = *(const half8*)(As + ra * 64 + ca * 8);
        int rb = wc * 64 + t * 16 + l15;
        int cb = (kh * 4 + l16) ^ (rb & 7);
        bhf[t] = *(const half8*)(Bhs + rb * 64 + cb * 8);
      }
#pragma unroll
      for (int i = 0; i < 4; ++i)
#pragma unroll
        for (int j = 0; j < 4; ++j)
          acc[i][j] = __builtin_amdgcn_mfma_f32_16x16x32_f16(af[i], bhf[j], acc[i][j], 0, 0, 0);
    }
    __syncthreads();
  }
  const int hh = n0 >> 7;   // head of this col-block (NC=512)
#pragma unroll
  for (int i = 0; i < 4; ++i) {
#pragma unroll
    for (int r = 0; r < 4; ++r) {
      int row = m0 + wr * 64 + i * 16 + l16 * 4 + r;
      if (DOTS) {
        float vs = 0.f, vd = 0.f;
#pragma unroll
        for (int j = 0; j < 4; ++j) {
          vs = fmaf(acc[i][j][r], a_s[j], vs);
          vd = fmaf(acc[i][j][r], a_d[j], vd);
        }
#pragma unroll
        for (int o = 1; o < 16; o <<= 1) { vs += __shfl_xor(vs, o); vd += __shfl_xor(vd, o); }
        if (l15 == 0 && row < M) {
          sspS[(size_t)wc * (NN * 4) + row * 4 + hh] = vs;
          sspD[(size_t)wc * (NN * 4) + row * 4 + hh] = vd;
        }
      }
      if (row >= M) continue;
#pragma unroll
      for (int j = 0; j < 4; ++j) {
        int col = n0 + wc * 64 + j * 16 + l15;
        C[(size_t)row * NC + col] = __float2half(acc[i][j][r]);
      }
    }
  }
}

// ---------------- combine the two wc-partials into ssrc/sdst ----------------
__global__ __launch_bounds__(256) void k_scomb(const float* __restrict__ sspS,
                                               const float* __restrict__ sspD,
                                               float* __restrict__ ssrc,
                                               float* __restrict__ sdst) {
  int idx = blockIdx.x * 256 + threadIdx.x;
  if (idx < NN * 4) {
    ssrc[idx] = sspS[idx] + sspS[NN * 4 + idx];
    sdst[idx] = sspD[idx] + sspD[NN * 4 + idx];
  }
}

// ---------------- split-K MFMA partial GEMM (MLP head): part[kz][M][NC] f32 ----------------
__global__ __launch_bounds__(256) void k_mfmaK(const __half* __restrict__ A,
                                               const __half* __restrict__ Bh,
                                               float* __restrict__ part,
                                               int M, int K, int NC, int Kc) {
  __shared__ __half lds[2 * 128 * 64];
  __half* As  = lds;
  __half* Bhs = lds + 8192;
  const int tid = threadIdx.x, l = tid & 63, w = tid >> 6;
  const int wr = w >> 1, wc = w & 1;
  const int m0 = blockIdx.y * 128, n0 = blockIdx.x * 128;
  const int kz = blockIdx.z;
  const int kb = kz * Kc, ke = kb + Kc;
  const int l15 = l & 15, l16 = l >> 4;
  const int sr = l >> 3;
  const int ss = (l & 7) ^ sr;

  f32x4 acc[4][4] = {};
  for (int k0 = kb; k0 < ke; k0 += 64) {
#pragma unroll
    for (int j = 0; j < 4; ++j) {
      int rbase = j * 32 + w * 8;
      int rl = rbase + sr;
      int gA = min(m0 + rl, M - 1);
      int gB = n0 + rl;
      const size_t ko = (size_t)(k0 + ss * 8);
      ldg2lds16(A  + (size_t)gA * K + ko, As  + rbase * 64);
      ldg2lds16(Bh + (size_t)gB * K + ko, Bhs + rbase * 64);
    }
    __syncthreads();
#pragma unroll
    for (int kh = 0; kh < 2; ++kh) {
      half8 af[4], bhf[4];
#pragma unroll
      for (int t = 0; t < 4; ++t) {
        int ra = wr * 64 + t * 16 + l15;
        int ca = (kh * 4 + l16) ^ (ra & 7);
        af[t] = *(const half8*)(As + ra * 64 + ca * 8);
        int rb = wc * 64 + t * 16 + l15;
        int cb = (kh * 4 + l16) ^ (rb & 7);
        bhf[t] = *(const half8*)(Bhs + rb * 64 + cb * 8);
      }
#pragma unroll
      for (int i = 0; i < 4; ++i)
#pragma unroll
        for (int j = 0; j < 4; ++j)
          acc[i][j] = __builtin_amdgcn_mfma_f32_16x16x32_f16(af[i], bhf[j], acc[i][j], 0, 0, 0);
    }
    __syncthreads();
  }
  float* pz = part + (size_t)kz * M * NC;
#pragma unroll
  for (int i = 0; i < 4; ++i) {
#pragma unroll
    for (int r = 0; r < 4; ++r) {
      int row = m0 + wr * 64 + i * 16 + l16 * 4 + r;
      if (row >= M) continue;
#pragma unroll
      for (int j = 0; j < 4; ++j) {
        int col = n0 + wc * 64 + j * 16 + l15;
        pz[(size_t)row * NC + col] = acc[i][j][r];
      }
    }
  }
}

// ---------------- finalize p1: sum 8 partials + bias + GELU -> f16 ----------------
__global__ __launch_bounds__(256) void k_fin_gelu(const float* __restrict__ part,
                                                  const float* __restrict__ bias,
                                                  __half* __restrict__ outh) {
  int idx = blockIdx.x * 256 + threadIdx.x;   // [GG*1024)
  if (idx >= GG * 1024) return;
  int c = idx & 1023;
  float v = bias[c];
#pragma unroll
  for (int z = 0; z < 8; ++z) v += part[(size_t)z * GG * 1024 + idx];
  v = 0.5f * v * (1.0f + erff(v * 0.70710678118654752f));
  outh[idx] = __float2half_rn(v);
}

// ---------------- finalize p2 + row L2 normalize: one block per graph ----------------
__global__ __launch_bounds__(256) void k_fin_l2(const float* __restrict__ part,
                                                const float* __restrict__ bias,
                                                float* __restrict__ out) {
  int g = blockIdx.x, t = threadIdx.x;   // t < 256 = OUTD
  float v = bias[t];
#pragma unroll
  for (int z = 0; z < 8; ++z) v += part[(size_t)z * GG * OUTD + g * OUTD + t];
  float q = v * v;
#pragma unroll
  for (int o = 32; o; o >>= 1) q += __shfl_xor(q, o);
  __shared__ float w[4];
  int wv = t >> 6, ln = t & 63;
  if (ln == 0) w[wv] = q;
  __syncthreads();
  float tot = w[0] + w[1] + w[2] + w[3];
  float nrm = fmaxf(sqrtf(tot), 1e-12f);
  out[(size_t)g * OUTD + t] = v / nrm;
}

// ---------------- per-edge packed records: {src[15b] << 16 | f16(alpha)}; zero pads ----------------
__global__ __launch_bounds__(256) void k_eweight(const float* __restrict__ ssrc,
                                                 const float* __restrict__ sdst,
                                                 const int* __restrict__ poff,
                                                 const int* __restrict__ cnt_,
                                                 const int* __restrict__ csr,
                                                 unsigned* __restrict__ ewk) {
  int wv = threadIdx.x >> 6, ln = threadIdx.x & 63;
  int n = blockIdx.x * 4 + wv;
  int beg = poff[n], pend = poff[n + 1];
  int deg = cnt_[n];
  float4 sd4 = *(const float4*)(sdst + (size_t)n * 4);
  float4 wreg[2];
  int    skreg[2];
  float d0 = 0.f, d1 = 0.f, d2 = 0.f, d3 = 0.f;
  int cnt = 0;
  for (int j = ln; j < deg; j += 64) {
    int sk = csr[beg + j];
    float4 s = *(const float4*)(ssrc + (size_t)sk * 4);
    float e0 = s.x + sd4.x; e0 = (e0 > 0.f) ? e0 : 0.2f * e0;
    float e1 = s.y + sd4.y; e1 = (e1 > 0.f) ? e1 : 0.2f * e1;
    float e2 = s.z + sd4.z; e2 = (e2 > 0.f) ? e2 : 0.2f * e2;
    float e3 = s.w + sd4.w; e3 = (e3 > 0.f) ? e3 : 0.2f * e3;
    float4 wv4 = make_float4(__expf(e0), __expf(e1), __expf(e2), __expf(e3));
    if (cnt < 2) { wreg[cnt] = wv4; skreg[cnt] = sk; }
    ++cnt;
    d0 += wv4.x; d1 += wv4.y; d2 += wv4.z; d3 += wv4.w;
  }
#pragma unroll
  for (int o = 32; o; o >>= 1) {
    d0 += __shfl_xor(d0, o); d1 += __shfl_xor(d1, o);
    d2 += __shfl_xor(d2, o); d3 += __shfl_xor(d3, o);
  }
  float r0 = 1.0f / d0, r1 = 1.0f / d1, r2 = 1.0f / d2, r3 = 1.0f / d3;
  cnt = 0;
  int plen = pend - beg;
  for (int j = ln; j < plen; j += 64) {
    int k = beg + j;
    if (j < deg) {
      float4 wv4;
      int sk;
      if (cnt < 2) { wv4 = wreg[cnt]; sk = skreg[cnt]; }
      else {
        sk = csr[k];
        float4 s = *(const float4*)(ssrc + (size_t)sk * 4);
        float e0 = s.x + sd4.x; e0 = (e0 > 0.f) ? e0 : 0.2f * e0;
        float e1 = s.y + sd4.y; e1 = (e1 > 0.f) ? e1 : 0.2f * e1;
        float e2 = s.z + sd4.z; e2 = (e2 > 0.f) ? e2 : 0.2f * e2;
        float e3 = s.w + sd4.w; e3 = (e3 > 0.f) ? e3 : 0.2f * e3;
        wv4 = make_float4(__expf(e0), __expf(e1), __expf(e2), __expf(e3));
      }
      ++cnt;
      unsigned sh = (unsigned)sk << 16;
      ewk[k]           = sh | (unsigned)__half_as_ushort(__float2half_rn(wv4.x * r0));
      ewk[ETP + k]     = sh | (unsigned)__half_as_ushort(__float2half_rn(wv4.y * r1));
      ewk[2 * ETP + k] = sh | (unsigned)__half_as_ushort(__float2half_rn(wv4.z * r2));
      ewk[3 * ETP + k] = sh | (unsigned)__half_as_ushort(__float2half_rn(wv4.w * r3));
    } else {
      ewk[k]           = 0u;
      ewk[ETP + k]     = 0u;
      ewk[2 * ETP + k] = 0u;
      ewk[3 * ETP + k] = 0u;
    }
  }
}

// ---------------- channel-split aggregation: padded slots + psq epilogue ----------------
// cb = blockIdx % 8 pins a 64-ch slice to one XCD's L2. Lane l = (g=l>>4 edge-group, q=l&15 ch-quad).
__device__ __forceinline__ void acc4mix(float* acc, unsigned rec, const uint2& x) {
  asm("v_fma_mix_f32 %0, %1, %2, %0 op_sel:[0,0,0] op_sel_hi:[1,1,0]" : "+v"(acc[0]) : "v"(rec), "v"(x.x));
  asm("v_fma_mix_f32 %0, %1, %2, %0 op_sel:[0,1,0] op_sel_hi:[1,1,0]" : "+v"(acc[1]) : "v"(rec), "v"(x.x));
  asm("v_fma_mix_f32 %0, %1, %2, %0 op_sel:[0,0,0] op_sel_hi:[1,1,0]" : "+v"(acc[2]) : "v"(rec), "v"(x.y));
  asm("v_fma_mix_f32 %0, %1, %2, %0 op_sel:[0,1,0] op_sel_hi:[1,1,0]" : "+v"(acc[3]) : "v"(rec), "v"(x.y));
}

__global__ __launch_bounds__(256, 8) void k_aggc(const __half* __restrict__ xp16,
                                                 const unsigned* __restrict__ ewk,
                                                 const int* __restrict__ poff,
                                                 const float* __restrict__ bias,
                                                 __half* __restrict__ xio,   // in: residual f16, out: pre-LN f16
                                                 float* __restrict__ psq) {  // [NN][8][2]
  const int bid = blockIdx.x;
  const int cb = bid & 7;
  const int chunk = bid >> 3;
  const int wv = threadIdx.x >> 6, l = threadIdx.x & 63;
  const int g = l >> 4, q = l & 15;
  const int h = cb >> 1;
  const int n = __builtin_amdgcn_readfirstlane(chunk * 4 + wv);
  const int beg = poff[n], pend = poff[n + 1];
  const unsigned* __restrict__ ewh = ewk + (size_t)h * ETP;
  const __half* __restrict__ xb = xp16 + cb * 64;     // wave-uniform base
  const unsigned qoff = (unsigned)q * 8;              // byte offset of channel quad

  // independent prefetches
  uint2 rres = *(const uint2*)(xio + (size_t)n * DD + cb * 64 + q * 4);
  float4 bi = *(const float4*)(bias + cb * 64 + q * 4);

  float acc[4] = {};
  {
    // ---- 5-group block, unconditional (slots always >= 20) ----
    unsigned r[5];
    uint2 x[5];
#pragma unroll
    for (int i = 0; i < 5; ++i) r[i] = ewh[beg + i * 4 + g];
#pragma unroll
    for (int i = 0; i < 5; ++i)
      x[i] = *(const uint2*)((const char*)xb + (((r[i] >> 6) & 0xFFFFFC00u) | qoff));
#pragma unroll
    for (int i = 0; i < 5; ++i) acc4mix(acc, r[i], x[i]);
  }
  // ---- tail (pdeg > 20), unconditional 4-steps ----
  for (int k = beg + 20; k < pend; k += 4) {
    unsigned rr = ewh[k + g];
    uint2 xx = *(const uint2*)((const char*)xb + (((rr >> 6) & 0xFFFFFC00u) | qoff));
    acc4mix(acc, rr, xx);
  }
  // reduce over the 4 edge-groups (strides 16, 32)
#pragma unroll
  for (int j = 0; j < 4; ++j) {
    acc[j] += __shfl_xor(acc[j], 16);
    acc[j] += __shfl_xor(acc[j], 32);
  }
  float2 fr0 = __half22float2(*(__half2*)&rres.x);
  float2 fr1 = __half22float2(*(__half2*)&rres.y);
  float o0 = acc[0] + bi.x + fr0.x;
  float o1 = acc[1] + bi.y + fr0.y;
  float o2 = acc[2] + bi.z + fr1.x;
  float o3 = acc[3] + bi.w + fr1.y;
  if (g == 0) {
    uint2 st;
    *(__half2*)&st.x = __floats2half2_rn(o0, o1);
    *(__half2*)&st.y = __floats2half2_rn(o2, o3);
    *(uint2*)(xio + (size_t)n * DD + cb * 64 + q * 4) = st;
  }
  float ps = o0 + o1 + o2 + o3;
  float pq = o0 * o0 + o1 * o1 + o2 * o2 + o3 * o3;
#pragma unroll
  for (int o2r = 1; o2r < 16; o2r <<= 1) { ps += __shfl_xor(ps, o2r); pq += __shfl_xor(pq, o2r); }
  if (l == 0) {
    psq[(size_t)n * 16 + cb * 2]     = ps;
    psq[(size_t)n * 16 + cb * 2 + 1] = pq;
  }
}

// ---------------- per-graph LN stats from psq (batch sorted; binary search range) ----------------
__device__ __forceinline__ int lowb(const int* a, int n, int key) {
  int lo = 0, hi = n;
  while (lo < hi) { int mid = (lo + hi) >> 1; if (a[mid] < key) lo = mid + 1; else hi = mid; }
  return lo;
}

__global__ __launch_bounds__(256) void k_stats2(const float* __restrict__ psq,
                                                const int* __restrict__ batch,
                                                float* __restrict__ gmu, float* __restrict__ grstd) {
  int g = blockIdx.x, tid = threadIdx.x;
  __shared__ int sb, se;
  __shared__ float rs[4], rq[4];
  if (tid == 0) { sb = lowb(batch, NN, g); se = lowb(batch, NN, g + 1); }
  __syncthreads();
  int b = sb, e = se;
  float ps = 0.f, pq = 0.f;
  for (int n = b + tid; n < e; n += 256) {
    const float4* p = (const float4*)(psq + (size_t)n * 16);
#pragma unroll
    for (int i = 0; i < 4; ++i) {
      float4 v = p[i];
      ps += v.x + v.z;
      pq += v.y + v.w;
    }
  }
#pragma unroll
  for (int o = 32; o; o >>= 1) { ps += __shfl_xor(ps, o); pq += __shfl_xor(pq, o); }
  int wv = tid >> 6, ln = tid & 63;
  if (ln == 0) { rs[wv] = ps; rq[wv] = pq; }
  __syncthreads();
  if (tid == 0) {
    float S = rs[0] + rs[1] + rs[2] + rs[3];
    float Q = rq[0] + rq[1] + rq[2] + rq[3];
    float cnt = fmaxf((float)(e - b) * (float)DD, 1.0f);
    float mu  = S / cnt;
    float var = fmaxf(Q / cnt - mu * mu, 0.0f);
    gmu[g]   = mu;
    grstd[g] = rsqrtf(var + 1e-5f);
  }
}

// ---------------- graph-LN normalize, f16 in / f16 out ----------------
__global__ __launch_bounds__(256) void k_norm(__half* __restrict__ x, const int* __restrict__ batch,
                                              const float* __restrict__ gmu, const float* __restrict__ grstd,
                                              const float* __restrict__ lnw, const float* __restrict__ lnb) {
  for (int i8 = blockIdx.x * 256 + threadIdx.x; i8 < NN * DD / 8; i8 += gridDim.x * 256) {
    int i = i8 * 8;
    int n = i >> 9, d = i & 511;
    int g = batch[n];
    float mu = gmu[g], rs = grstd[g];
    uint4 raw = *(uint4*)(x + i);
    __half2* hp = (__half2*)&raw;
    float4 w0 = *(const float4*)(lnw + d);
    float4 w1 = *(const float4*)(lnw + d + 4);
    float4 b0 = *(const float4*)(lnb + d);
    float4 b1 = *(const float4*)(lnb + d + 4);
    float wv[8] = {w0.x,w0.y,w0.z,w0.w,w1.x,w1.y,w1.z,w1.w};
    float bv[8] = {b0.x,b0.y,b0.z,b0.w,b1.x,b1.y,b1.z,b1.w};
#pragma unroll
    for (int j = 0; j < 4; ++j) {
      float2 f = __half22float2(hp[j]);
      f.x = (f.x - mu) * rs * wv[2*j]   + bv[2*j];
      f.y = (f.y - mu) * rs * wv[2*j+1] + bv[2*j+1];
      hp[j] = __floats2half2_rn(f.x, f.y);
    }
    *(uint4*)(x + i) = raw;
  }
}

// ---------------- pooling stage 1: per-(graph, slice) partials ----------------
__global__ __launch_bounds__(256) void k_poolp(const __half* __restrict__ x, const int* __restrict__ batch,
                                               float* __restrict__ pps, float* __restrict__ ppm) {
  int g = blockIdx.x, z = blockIdx.y, tid = threadIdx.x;
  __shared__ int sb, se;
  if (tid == 0) { sb = lowb(batch, NN, g); se = lowb(batch, NN, g + 1); }
  __syncthreads();
  int b = sb, e = se, cnt = e - b;
  int len = (cnt + 7) >> 3;
  int nb = b + z * len, ne = min(nb + len, e);
  float s0 = 0.f, s1 = 0.f, m0 = -INFINITY, m1 = -INFINITY;
  for (int n = nb; n < ne; ++n) {
    float v0 = __half2float(x[(size_t)n * DD + tid]);
    float v1 = __half2float(x[(size_t)n * DD + tid + 256]);
    s0 += v0; s1 += v1;
    m0 = fmaxf(m0, v0); m1 = fmaxf(m1, v1);
  }
  size_t o = ((size_t)g * 8 + z) * 512;
  pps[o + tid]       = s0;
  pps[o + tid + 256] = s1;
  ppm[o + tid]       = m0;
  ppm[o + tid + 256] = m1;
}

// ---------------- pooling stage 2: combine 8 slices -> f16 [G][1024] ----------------
__global__ __launch_bounds__(256) void k_poolc(const float* __restrict__ pps, const float* __restrict__ ppm,
                                               const int* __restrict__ batch, __half* __restrict__ pool16) {
  int g = blockIdx.x, tid = threadIdx.x;
  __shared__ int sb, se;
  if (tid == 0) { sb = lowb(batch, NN, g); se = lowb(batch, NN, g + 1); }
  __syncthreads();
  int cnt = se - sb;
  float s0 = 0.f, s1 = 0.f, m0 = -INFINITY, m1 = -INFINITY;
#pragma unroll
  for (int z = 0; z < 8; ++z) {
    size_t o = ((size_t)g * 8 + z) * 512;
    s0 += pps[o + tid];
    s1 += pps[o + tid + 256];
    m0 = fmaxf(m0, ppm[o + tid]);
    m1 = fmaxf(m1, ppm[o + tid + 256]);
  }
  float inv = 1.0f / (float)(cnt > 0 ? cnt : 1);
  pool16[(size_t)g * 1024 + tid]             = __float2half_rn(s0 * inv);
  pool16[(size_t)g * 1024 + tid + 256]       = __float2half_rn(s1 * inv);
  pool16[(size_t)g * 1024 + 512 + tid]       = __float2half_rn((cnt > 0) ? m0 : 0.f);
  pool16[(size_t)g * 1024 + 512 + tid + 256] = __float2half_rn((cnt > 0) ? m1 : 0.f);
}

// ---------------- launcher ----------------
extern "C" void kernel_launch(void* const* d_in, const int* in_sizes, int n_in,
                              void* d_out, int out_size, void* d_ws, size_t ws_size,
                              hipStream_t stream) {
  const int*   node_ids = (const int*)d_in[0];
  const int*   ei       = (const int*)d_in[1];
  const int*   batch    = (const int*)d_in[2];
  const float* emb      = (const float*)d_in[3];
  const float* W[4]  = {(const float*)d_in[4],  (const float*)d_in[10], (const float*)d_in[16], (const float*)d_in[22]};
  const float* AS[4] = {(const float*)d_in[5],  (const float*)d_in[11], (const float*)d_in[17], (const float*)d_in[23]};
  const float* AD[4] = {(const float*)d_in[6],  (const float*)d_in[12], (const float*)d_in[18], (const float*)d_in[24]};
  const float* BV[4] = {(const float*)d_in[7],  (const float*)d_in[13], (const float*)d_in[19], (const float*)d_in[25]};
  const float* LW[4] = {(const float*)d_in[8],  (const float*)d_in[14], (const float*)d_in[20], (const float*)d_in[26]};
  const float* LB[4] = {(const float*)d_in[9],  (const float*)d_in[15], (const float*)d_in[21], (const float*)d_in[27]};
  const float* res_w0 = (const float*)d_in[28];
  const float* p1w    = (const float*)d_in[29];
  const float* p1b    = (const float*)d_in[30];
  const float* p2w    = (const float*)d_in[31];
  const float* p2b    = (const float*)d_in[32];
  float* out = (float*)d_out;

  char* ws = (char*)d_ws;
  size_t pos = 0;
  auto alloc = [&](size_t bytes) -> char* {
    char* p = ws + pos;
    pos = (pos + bytes + 255) & ~size_t(255);
    return p;
  };
  __half* xr16  = (__half*)alloc((size_t)NN * DD * 2);   // unified residual / GEMM-A / pool input
  __half* xp16  = (__half*)alloc((size_t)NN * DD * 2);
  __half* x0f   = (__half*)alloc((size_t)NN * DEE * 2);
  float*  ssrc  = (float*)alloc((size_t)NN * 4 * 4);
  float*  sdst  = (float*)alloc((size_t)NN * 4 * 4);
  float*  sspS  = (float*)alloc((size_t)2 * NN * 4 * 4);
  float*  sspD  = (float*)alloc((size_t)2 * NN * 4 * 4);
  int*    poff  = (int*)alloc((size_t)(NN + 1) * 4);
  int*    cntb  = (int*)alloc((size_t)NN * 4);
  int*    ccur  = (int*)alloc((size_t)NN * 4);
  int*    csrc  = (int*)alloc((size_t)ETP * 4);
  unsigned* ewk = (unsigned*)alloc((size_t)ETP * 4 * 4); // 4 head planes of packed {src,f16 alpha}
  float*  psq   = (float*)alloc((size_t)NN * 16 * 4);
  float*  gmu   = (float*)alloc((size_t)GG * 4 * 2);
  float*  grstd = gmu + GG;
  // transposed f16 weights
  __half* w0t = (__half*)alloc((size_t)DEE * DD * 2);
  __half* rwt = (__half*)alloc((size_t)DEE * DD * 2);
  __half* wt[4] = {w0t, nullptr, nullptr, nullptr};
  for (int i = 1; i < 4; ++i) wt[i] = (__half*)alloc((size_t)DD * DD * 2);
  __half* p1t = (__half*)alloc((size_t)1024 * 1024 * 2);
  __half* p2t = (__half*)alloc((size_t)OUTD * 1024 * 2);
  __half* pool16 = (__half*)alloc((size_t)GG * 1024 * 2);
  __half* h1_16  = (__half*)alloc((size_t)GG * 1024 * 2);
  float*  pps    = (float*)alloc((size_t)GG * 8 * 512 * 4);  // 2 MB
  float*  ppm    = (float*)alloc((size_t)GG * 8 * 512 * 4);  // 2 MB
  float*  part1  = (float*)alloc((size_t)8 * GG * 1024 * 4); // 4 MB
  float*  part2  = (float*)alloc((size_t)8 * GG * OUTD * 4); // 1 MB
  (void)ws_size; (void)in_sizes; (void)n_in; (void)out_size;

  // ---- CSR (padded) + weight prep ----
  hipMemsetAsync(cntb, 0, (size_t)NN * 4, stream);
  hipMemsetAsync(ccur, 0, (size_t)NN * 4, stream);
  k_embf16<<<1250, 256, 0, stream>>>(node_ids, emb, x0f);
  k_count<<<1024, 256, 0, stream>>>(ei, cntb);
  k_scan<<<1, 1024, 0, stream>>>(cntb, poff);
  k_scatter<<<1024, 256, 0, stream>>>(ei, poff, ccur, csrc);
  k_wT16<<<dim3(16, 2),  256, 0, stream>>>(W[0],   w0t, DEE, DD);
  k_wT16<<<dim3(16, 2),  256, 0, stream>>>(res_w0, rwt, DEE, DD);
  for (int i = 1; i < 4; ++i)
    k_wT16<<<dim3(16, 16), 256, 0, stream>>>(W[i], wt[i], DD, DD);
  k_wT16<<<dim3(32, 32), 256, 0, stream>>>(p1w, p1t, 1024, 1024);
  k_wT16<<<dim3(8, 32),  256, 0, stream>>>(p2w, p2t, 1024, OUTD);

  // ---- L0 projections (xp GEMM carries fused attention dots via wc-partials) ----
  k_mfma3<1><<<dim3(4, 157), 256, 0, stream>>>(x0f, w0t, xp16, NN, DEE, DD,
                                               AS[0], AD[0], sspS, sspD);
  k_mfma3<0><<<dim3(4, 157), 256, 0, stream>>>(x0f, rwt, xr16, NN, DEE, DD,
                                               nullptr, nullptr, nullptr, nullptr);
  k_scomb<<<(NN * 4 + 255) / 256, 256, 0, stream>>>(sspS, sspD, ssrc, sdst);

  // ---- 4 GAT layers ----
  for (int L = 0; L < 4; ++L) {
    k_eweight<<<NN / 4, 256, 0, stream>>>(ssrc, sdst, poff, cntb, csrc, ewk);
    k_aggc<<<NN * 2, 256, 0, stream>>>(xp16, ewk, poff, BV[L], xr16, psq);
    k_stats2<<<GG, 256, 0, stream>>>(psq, batch, gmu, grstd);
    k_norm<<<2048, 256, 0, stream>>>(xr16, batch, gmu, grstd, LW[L], LB[L]);
    if (L < 3) {
      k_mfma3<1><<<dim3(4, 157), 256, 0, stream>>>(xr16, wt[L + 1], xp16, NN, DD, DD,
                                                   AS[L + 1], AD[L + 1], sspS, sspD);
      k_scomb<<<(NN * 4 + 255) / 256, 256, 0, stream>>>(sspS, sspD, ssrc, sdst);
    }
  }

  // ---- pool (2-stage) + MLP head (split-K) + fused finalize/normalize ----
  k_poolp<<<dim3(GG, 8), 256, 0, stream>>>(xr16, batch, pps, ppm);
  k_poolc<<<GG, 256, 0, stream>>>(pps, ppm, batch, pool16);
  k_mfmaK<<<dim3(8, 1, 8), 256, 0, stream>>>(pool16, p1t, part1, GG, 1024, 1024, 128);
  k_fin_gelu<<<512, 256, 0, stream>>>(part1, p1b, h1_16);
  k_mfmaK<<<dim3(2, 1, 8), 256, 0, stream>>>(h1_16, p2t, part2, GG, 1024, OUTD, 128);
  k_fin_l2<<<GG, 256, 0, stream>>>(part2, p2b, out);
}

// Round 18
// 533.986 us; speedup vs baseline: 1.3170x; 1.1924x over previous
//
#include <hip/hip_runtime.h>
#include <hip/hip_fp16.h>
#include <math.h>

constexpr int NN   = 20000;
constexpr int EE   = 320000;
constexpr int ET   = EE + NN;   // 340000 with self loops
constexpr int GG   = 128;
constexpr int DEE  = 64;
constexpr int DD   = 512;
constexpr int OUTD = 256;

using half8 = __attribute__((ext_vector_type(8))) _Float16;
using f32x4 = __attribute__((ext_vector_type(4))) float;

// ---- async global->LDS 16B (wave-uniform LDS base + lane*16 implicit) ----
__device__ __forceinline__ void ldg2lds16(const void* g, void* l) {
  __builtin_amdgcn_global_load_lds((const __attribute__((address_space(1))) unsigned*)g,
                                   (__attribute__((address_space(3))) unsigned*)l, 16, 0, 0);
}

// ---------------- embedding gather -> f16 ----------------
__global__ __launch_bounds__(256) void k_embf16(const int* __restrict__ ids,
                                                const float* __restrict__ emb,
                                                __half* __restrict__ x0) {
  for (int i = blockIdx.x * 256 + threadIdx.x; i < NN * 16; i += gridDim.x * 256) {
    int n = i >> 4, q = (i & 15) * 4;
    float4 v = *(const float4*)(emb + (size_t)ids[n] * DEE + q);
    __half2* o = (__half2*)(x0 + (size_t)n * DEE + q);
    o[0] = __floats2half2_rn(v.x, v.y);
    o[1] = __floats2half2_rn(v.z, v.w);
  }
}

// ---------------- weight transpose -> f16: T[n][k] = W[k][n] ----------------
__global__ __launch_bounds__(256) void k_wT16(const float* __restrict__ W,
                                              __half* __restrict__ Th,
                                              int K, int N) {
  __shared__ float t[32][33];
  int n0 = blockIdx.x * 32, k0 = blockIdx.y * 32;
  int c = threadIdx.x & 31, r4 = threadIdx.x >> 5;
  for (int rr = 0; rr < 32; rr += 8)
    t[rr + r4][c] = W[(size_t)(k0 + rr + r4) * N + n0 + c];
  __syncthreads();
  for (int rr = 0; rr < 32; rr += 8) {
    int n = n0 + rr + r4, k = k0 + c;
    Th[(size_t)n * K + k] = __float2half_rn(t[c][rr + r4]);
  }
}

// ---------------- CSR build ----------------
__global__ __launch_bounds__(256) void k_count(const int* __restrict__ ei, int* __restrict__ cnt) {
  for (int k = blockIdx.x * 256 + threadIdx.x; k < ET; k += gridDim.x * 256) {
    int d = (k < EE) ? ei[EE + k] : (k - EE);
    atomicAdd(&cnt[d], 1);
  }
}

__global__ __launch_bounds__(1024) void k_scan(const int* __restrict__ cnt, int* __restrict__ off) {
  __shared__ int part[1024];
  int tid = threadIdx.x;
  constexpr int CH = (NN + 1023) / 1024;  // 20
  int base = tid * CH;
  int s = 0;
  for (int i = 0; i < CH; ++i) { int idx = base + i; if (idx < NN) s += cnt[idx]; }
  part[tid] = s;
  __syncthreads();
  for (int o = 1; o < 1024; o <<= 1) {
    int add = (tid >= o) ? part[tid - o] : 0;
    int v = part[tid];
    __syncthreads();
    part[tid] = v + add;
    __syncthreads();
  }
  int run = (tid == 0) ? 0 : part[tid - 1];
  for (int i = 0; i < CH; ++i) {
    int idx = base + i;
    if (idx < NN) { off[idx] = run; run += cnt[idx]; }
  }
  if (tid == 1023) off[NN] = ET;
}

__global__ __launch_bounds__(256) void k_scatter(const int* __restrict__ ei, const int* __restrict__ off,
                                                 int* __restrict__ cur, int* __restrict__ csrc) {
  for (int k = blockIdx.x * 256 + threadIdx.x; k < ET; k += gridDim.x * 256) {
    int s = (k < EE) ? ei[k]      : (k - EE);
    int d = (k < EE) ? ei[EE + k] : (k - EE);
    int p = atomicAdd(&cur[d], 1);
    csrc[off[d] + p] = s;
  }
}

// ---------------- f16 MFMA GEMM (layers): C[M,NC] = A[M,K] @ B, f16 out ----------------
// Single-f16 B. DOTS=1: fused attention dots -> per-wc partials.
template<int DOTS>
__global__ __launch_bounds__(256) void k_mfma3(const __half* __restrict__ A,
                                               const __half* __restrict__ Bh,
                                               __half* __restrict__ C,
                                               int M, int K, int NC,
                                               const float* __restrict__ asw,
                                               const float* __restrict__ adw,
                                               float* __restrict__ sspS,
                                               float* __restrict__ sspD) {
  __shared__ __half lds[2 * 128 * 64];   // A | Bh, 16 KB each
  __half* As  = lds;
  __half* Bhs = lds + 8192;
  const int tid = threadIdx.x, l = tid & 63, w = tid >> 6;
  const int wr = w >> 1, wc = w & 1;
  const int m0 = blockIdx.y * 128, n0 = blockIdx.x * 128;
  const int l15 = l & 15, l16 = l >> 4;
  const int sr = l >> 3;
  const int ss = (l & 7) ^ sr;

  float a_s[4], a_d[4];
  if (DOTS) {
#pragma unroll
    for (int j = 0; j < 4; ++j) {
      int col = n0 + wc * 64 + j * 16 + l15;   // flat [H*C] index
      a_s[j] = asw[col];
      a_d[j] = adw[col];
    }
  }

  f32x4 acc[4][4] = {};
  for (int k0 = 0; k0 < K; k0 += 64) {
#pragma unroll
    for (int j = 0; j < 4; ++j) {
      int rbase = j * 32 + w * 8;
      int rl = rbase + sr;
      int gA = min(m0 + rl, M - 1);
      int gB = n0 + rl;
      const size_t ko = (size_t)(k0 + ss * 8);
      ldg2lds16(A  + (size_t)gA * K + ko, As  + rbase * 64);
      ldg2lds16(Bh + (size_t)gB * K + ko, Bhs + rbase * 64);
    }
    __syncthreads();
#pragma unroll
    for (int kh = 0; kh < 2; ++kh) {
      half8 af[4], bhf[4];
#pragma unroll
      for (int t = 0; t < 4; ++t) {
        int ra = wr * 64 + t * 16 + l15;
        int ca = (kh * 4 + l16) ^ (ra & 7);
        af[t] = *(const half8*)(As + ra * 64 + ca * 8);
        int rb = wc * 64 + t * 16 + l15;
        int cb = (kh * 4 + l16) ^ (rb & 7);
        bhf[t] = *(const half8*)(Bhs + rb * 64 + cb * 8);
      }
#pragma unroll
      for (int i = 0; i < 4; ++i)
#pragma unroll
        for (int j = 0; j < 4; ++j)
          acc[i][j] = __builtin_amdgcn_mfma_f32_16x16x32_f16(af[i], bhf[j], acc[i][j], 0, 0, 0);
    }
    __syncthreads();
  }
  const int hh = n0 >> 7;   // head of this col-block (NC=512)
#pragma unroll
  for (int i = 0; i < 4; ++i) {
#pragma unroll
    for (int r = 0; r < 4; ++r) {
      int row = m0 + wr * 64 + i * 16 + l16 * 4 + r;
      if (DOTS) {
        float vs = 0.f, vd = 0.f;
#pragma unroll
        for (int j = 0; j < 4; ++j) {
          vs = fmaf(acc[i][j][r], a_s[j], vs);
          vd = fmaf(acc[i][j][r], a_d[j], vd);
        }
#pragma unroll
        for (int o = 1; o < 16; o <<= 1) { vs += __shfl_xor(vs, o); vd += __shfl_xor(vd, o); }
        if (l15 == 0 && row < M) {
          sspS[(size_t)wc * (NN * 4) + row * 4 + hh] = vs;
          sspD[(size_t)wc * (NN * 4) + row * 4 + hh] = vd;
        }
      }
      if (row >= M) continue;
#pragma unroll
      for (int j = 0; j < 4; ++j) {
        int col = n0 + wc * 64 + j * 16 + l15;
        C[(size_t)row * NC + col] = __float2half(acc[i][j][r]);
      }
    }
  }
}

// ---------------- combine the two wc-partials into ssrc/sdst ----------------
__global__ __launch_bounds__(256) void k_scomb(const float* __restrict__ sspS,
                                               const float* __restrict__ sspD,
                                               float* __restrict__ ssrc,
                                               float* __restrict__ sdst) {
  int idx = blockIdx.x * 256 + threadIdx.x;
  if (idx < NN * 4) {
    ssrc[idx] = sspS[idx] + sspS[NN * 4 + idx];
    sdst[idx] = sspD[idx] + sspD[NN * 4 + idx];
  }
}

// ---------------- split-K MFMA partial GEMM (MLP head): part[kz][M][NC] f32 ----------------
__global__ __launch_bounds__(256) void k_mfmaK(const __half* __restrict__ A,
                                               const __half* __restrict__ Bh,
                                               float* __restrict__ part,
                                               int M, int K, int NC, int Kc) {
  __shared__ __half lds[2 * 128 * 64];
  __half* As  = lds;
  __half* Bhs = lds + 8192;
  const int tid = threadIdx.x, l = tid & 63, w = tid >> 6;
  const int wr = w >> 1, wc = w & 1;
  const int m0 = blockIdx.y * 128, n0 = blockIdx.x * 128;
  const int kz = blockIdx.z;
  const int kb = kz * Kc, ke = kb + Kc;
  const int l15 = l & 15, l16 = l >> 4;
  const int sr = l >> 3;
  const int ss = (l & 7) ^ sr;

  f32x4 acc[4][4] = {};
  for (int k0 = kb; k0 < ke; k0 += 64) {
#pragma unroll
    for (int j = 0; j < 4; ++j) {
      int rbase = j * 32 + w * 8;
      int rl = rbase + sr;
      int gA = min(m0 + rl, M - 1);
      int gB = n0 + rl;
      const size_t ko = (size_t)(k0 + ss * 8);
      ldg2lds16(A  + (size_t)gA * K + ko, As  + rbase * 64);
      ldg2lds16(Bh + (size_t)gB * K + ko, Bhs + rbase * 64);
    }
    __syncthreads();
#pragma unroll
    for (int kh = 0; kh < 2; ++kh) {
      half8 af[4], bhf[4];
#pragma unroll
      for (int t = 0; t < 4; ++t) {
        int ra = wr * 64 + t * 16 + l15;
        int ca = (kh * 4 + l16) ^ (ra & 7);
        af[t] = *(const half8*)(As + ra * 64 + ca * 8);
        int rb = wc * 64 + t * 16 + l15;
        int cb = (kh * 4 + l16) ^ (rb & 7);
        bhf[t] = *(const half8*)(Bhs + rb * 64 + cb * 8);
      }
#pragma unroll
      for (int i = 0; i < 4; ++i)
#pragma unroll
        for (int j = 0; j < 4; ++j)
          acc[i][j] = __builtin_amdgcn_mfma_f32_16x16x32_f16(af[i], bhf[j], acc[i][j], 0, 0, 0);
    }
    __syncthreads();
  }
  float* pz = part + (size_t)kz * M * NC;
#pragma unroll
  for (int i = 0; i < 4; ++i) {
#pragma unroll
    for (int r = 0; r < 4; ++r) {
      int row = m0 + wr * 64 + i * 16 + l16 * 4 + r;
      if (row >= M) continue;
#pragma unroll
      for (int j = 0; j < 4; ++j) {
        int col = n0 + wc * 64 + j * 16 + l15;
        pz[(size_t)row * NC + col] = acc[i][j][r];
      }
    }
  }
}

// ---------------- finalize p1: sum 8 partials + bias + GELU -> f16 ----------------
__global__ __launch_bounds__(256) void k_fin_gelu(const float* __restrict__ part,
                                                  const float* __restrict__ bias,
                                                  __half* __restrict__ outh) {
  int idx = blockIdx.x * 256 + threadIdx.x;   // [GG*1024)
  if (idx >= GG * 1024) return;
  int c = idx & 1023;
  float v = bias[c];
#pragma unroll
  for (int z = 0; z < 8; ++z) v += part[(size_t)z * GG * 1024 + idx];
  v = 0.5f * v * (1.0f + erff(v * 0.70710678118654752f));
  outh[idx] = __float2half_rn(v);
}

// ---------------- finalize p2 + row L2 normalize: one block per graph ----------------
__global__ __launch_bounds__(256) void k_fin_l2(const float* __restrict__ part,
                                                const float* __restrict__ bias,
                                                float* __restrict__ out) {
  int g = blockIdx.x, t = threadIdx.x;   // t < 256 = OUTD
  float v = bias[t];
#pragma unroll
  for (int z = 0; z < 8; ++z) v += part[(size_t)z * GG * OUTD + g * OUTD + t];
  float q = v * v;
#pragma unroll
  for (int o = 32; o; o >>= 1) q += __shfl_xor(q, o);
  __shared__ float w[4];
  int wv = t >> 6, ln = t & 63;
  if (ln == 0) w[wv] = q;
  __syncthreads();
  float tot = w[0] + w[1] + w[2] + w[3];
  float nrm = fmaxf(sqrtf(tot), 1e-12f);
  out[(size_t)g * OUTD + t] = v / nrm;
}

// ---------------- per-edge packed records: {src[15b] << 16 | f16(alpha)} ----------------
// alpha pre-normalized (w/den). Planar per head for XCD-local reads.
__global__ __launch_bounds__(256) void k_eweight(const float* __restrict__ ssrc,
                                                 const float* __restrict__ sdst,
                                                 const int* __restrict__ off,
                                                 const int* __restrict__ csr,
                                                 unsigned* __restrict__ ewk) {
  int wv = threadIdx.x >> 6, ln = threadIdx.x & 63;
  int n = blockIdx.x * 4 + wv;
  int beg = off[n], end = off[n + 1];
  float4 sd4 = *(const float4*)(sdst + (size_t)n * 4);
  float4 wreg[2];
  int    skreg[2];
  float d0 = 0.f, d1 = 0.f, d2 = 0.f, d3 = 0.f;
  int cnt = 0;
  for (int k = beg + ln; k < end; k += 64) {
    int sk = csr[k];
    float4 s = *(const float4*)(ssrc + (size_t)sk * 4);
    float e0 = s.x + sd4.x; e0 = (e0 > 0.f) ? e0 : 0.2f * e0;
    float e1 = s.y + sd4.y; e1 = (e1 > 0.f) ? e1 : 0.2f * e1;
    float e2 = s.z + sd4.z; e2 = (e2 > 0.f) ? e2 : 0.2f * e2;
    float e3 = s.w + sd4.w; e3 = (e3 > 0.f) ? e3 : 0.2f * e3;
    float4 wv4 = make_float4(__expf(e0), __expf(e1), __expf(e2), __expf(e3));
    if (cnt < 2) { wreg[cnt] = wv4; skreg[cnt] = sk; }
    ++cnt;
    d0 += wv4.x; d1 += wv4.y; d2 += wv4.z; d3 += wv4.w;
  }
#pragma unroll
  for (int o = 32; o; o >>= 1) {
    d0 += __shfl_xor(d0, o); d1 += __shfl_xor(d1, o);
    d2 += __shfl_xor(d2, o); d3 += __shfl_xor(d3, o);
  }
  float r0 = 1.0f / d0, r1 = 1.0f / d1, r2 = 1.0f / d2, r3 = 1.0f / d3;
  cnt = 0;
  for (int k = beg + ln; k < end; k += 64) {
    float4 wv4;
    int sk;
    if (cnt < 2) { wv4 = wreg[cnt]; sk = skreg[cnt]; }
    else {
      sk = csr[k];
      float4 s = *(const float4*)(ssrc + (size_t)sk * 4);
      float e0 = s.x + sd4.x; e0 = (e0 > 0.f) ? e0 : 0.2f * e0;
      float e1 = s.y + sd4.y; e1 = (e1 > 0.f) ? e1 : 0.2f * e1;
      float e2 = s.z + sd4.z; e2 = (e2 > 0.f) ? e2 : 0.2f * e2;
      float e3 = s.w + sd4.w; e3 = (e3 > 0.f) ? e3 : 0.2f * e3;
      wv4 = make_float4(__expf(e0), __expf(e1), __expf(e2), __expf(e3));
    }
    ++cnt;
    unsigned sh = (unsigned)sk << 16;
    ewk[k]          = sh | (unsigned)__half_as_ushort(__float2half_rn(wv4.x * r0));
    ewk[ET + k]     = sh | (unsigned)__half_as_ushort(__float2half_rn(wv4.y * r1));
    ewk[2 * ET + k] = sh | (unsigned)__half_as_ushort(__float2half_rn(wv4.z * r2));
    ewk[3 * ET + k] = sh | (unsigned)__half_as_ushort(__float2half_rn(wv4.w * r3));
  }
}

// ---------------- channel-split aggregation: 4 edge-groups x 16 ch-quads, 5-deep block ----------------
// cb = blockIdx % 8 pins a 64-ch slice to one XCD's L2. Lane l = (g=l>>4 edge-group, q=l&15 ch-quad).
__device__ __forceinline__ void acc4mix(float* acc, unsigned rec, const uint2& x) {
  asm("v_fma_mix_f32 %0, %1, %2, %0 op_sel:[0,0,0] op_sel_hi:[1,1,0]" : "+v"(acc[0]) : "v"(rec), "v"(x.x));
  asm("v_fma_mix_f32 %0, %1, %2, %0 op_sel:[0,1,0] op_sel_hi:[1,1,0]" : "+v"(acc[1]) : "v"(rec), "v"(x.x));
  asm("v_fma_mix_f32 %0, %1, %2, %0 op_sel:[0,0,0] op_sel_hi:[1,1,0]" : "+v"(acc[2]) : "v"(rec), "v"(x.y));
  asm("v_fma_mix_f32 %0, %1, %2, %0 op_sel:[0,1,0] op_sel_hi:[1,1,0]" : "+v"(acc[3]) : "v"(rec), "v"(x.y));
}

__global__ __launch_bounds__(256, 8) void k_aggc(const __half* __restrict__ xp16,
                                                 const unsigned* __restrict__ ewk,
                                                 const int* __restrict__ off,
                                                 const float* __restrict__ bias,
                                                 __half* __restrict__ xio,   // in: residual f16, out: pre-LN f16
                                                 float* __restrict__ psq) {  // [NN][8][2]
  const int bid = blockIdx.x;
  const int cb = bid & 7;
  const int chunk = bid >> 3;
  const int wv = threadIdx.x >> 6, l = threadIdx.x & 63;
  const int g = l >> 4, q = l & 15;
  const int h = cb >> 1;
  const int n = __builtin_amdgcn_readfirstlane(chunk * 4 + wv);
  const int beg = off[n], end = off[n + 1];
  const unsigned* __restrict__ ewh = ewk + (size_t)h * ET;
  const __half* __restrict__ xb = xp16 + cb * 64;     // wave-uniform base
  const unsigned qoff = (unsigned)q * 8;              // byte offset of channel quad

  // independent prefetches
  uint2 rres = *(const uint2*)(xio + (size_t)n * DD + cb * 64 + q * 4);
  float4 bi = *(const float4*)(bias + cb * 64 + q * 4);

  float acc[4] = {};
  {
    // ---- 5-group block (covers deg<=20; 5 record + 5 x loads in flight) ----
    unsigned r[5];
    uint2 x[5];
#pragma unroll
    for (int i = 0; i < 5; ++i) {
      int e = beg + i * 4 + g;
      unsigned rr = ewh[min(e, end - 1)];
      r[i] = (e < end) ? rr : 0u;
    }
#pragma unroll
    for (int i = 0; i < 5; ++i)
      x[i] = *(const uint2*)((const char*)xb + (((r[i] >> 6) & 0xFFFFFC00u) | qoff));
#pragma unroll
    for (int i = 0; i < 5; ++i) acc4mix(acc, r[i], x[i]);
  }
  // ---- tail (deg > 20), 2-deep pipeline, step 4 ----
  if (beg + 20 < end) {
    int k = beg + 20;
    unsigned rA = ewh[min(k + g, end - 1)];
    unsigned rB = ewh[min(k + 4 + g, end - 1)];
    for (; k + 4 < end; k += 4) {
      rA = ((k + g) < end) ? rA : 0u;
      uint2 xA = *(const uint2*)((const char*)xb + (((rA >> 6) & 0xFFFFFC00u) | qoff));
      unsigned rN = ewh[min(k + 8 + g, end - 1)];
      acc4mix(acc, rA, xA);
      rA = rB; rB = rN;
    }
    rA = ((k + g) < end) ? rA : 0u;
    uint2 xA = *(const uint2*)((const char*)xb + (((rA >> 6) & 0xFFFFFC00u) | qoff));
    acc4mix(acc, rA, xA);
  }
  // reduce over the 4 edge-groups (strides 16, 32)
#pragma unroll
  for (int j = 0; j < 4; ++j) {
    acc[j] += __shfl_xor(acc[j], 16);
    acc[j] += __shfl_xor(acc[j], 32);
  }
  float2 fr0 = __half22float2(*(__half2*)&rres.x);
  float2 fr1 = __half22float2(*(__half2*)&rres.y);
  float o0 = acc[0] + bi.x + fr0.x;
  float o1 = acc[1] + bi.y + fr0.y;
  float o2 = acc[2] + bi.z + fr1.x;
  float o3 = acc[3] + bi.w + fr1.y;
  if (g == 0) {
    uint2 st;
    *(__half2*)&st.x = __floats2half2_rn(o0, o1);
    *(__half2*)&st.y = __floats2half2_rn(o2, o3);
    *(uint2*)(xio + (size_t)n * DD + cb * 64 + q * 4) = st;
  }
  float ps = o0 + o1 + o2 + o3;
  float pq = o0 * o0 + o1 * o1 + o2 * o2 + o3 * o3;
#pragma unroll
  for (int o2r = 1; o2r < 16; o2r <<= 1) { ps += __shfl_xor(ps, o2r); pq += __shfl_xor(pq, o2r); }
  if (l == 0) {
    psq[(size_t)n * 16 + cb * 2]     = ps;
    psq[(size_t)n * 16 + cb * 2 + 1] = pq;
  }
}

// ---------------- per-graph LN stats from psq (batch sorted; binary search range) ----------------
__device__ __forceinline__ int lowb(const int* a, int n, int key) {
  int lo = 0, hi = n;
  while (lo < hi) { int mid = (lo + hi) >> 1; if (a[mid] < key) lo = mid + 1; else hi = mid; }
  return lo;
}

__global__ __launch_bounds__(256) void k_stats2(const float* __restrict__ psq,
                                                const int* __restrict__ batch,
                                                float* __restrict__ gmu, float* __restrict__ grstd) {
  int g = blockIdx.x, tid = threadIdx.x;
  __shared__ int sb, se;
  __shared__ float rs[4], rq[4];
  if (tid == 0) { sb = lowb(batch, NN, g); se = lowb(batch, NN, g + 1); }
  __syncthreads();
  int b = sb, e = se;
  float ps = 0.f, pq = 0.f;
  for (int n = b + tid; n < e; n += 256) {
    const float4* p = (const float4*)(psq + (size_t)n * 16);
#pragma unroll
    for (int i = 0; i < 4; ++i) {
      float4 v = p[i];
      ps += v.x + v.z;
      pq += v.y + v.w;
    }
  }
#pragma unroll
  for (int o = 32; o; o >>= 1) { ps += __shfl_xor(ps, o); pq += __shfl_xor(pq, o); }
  int wv = tid >> 6, ln = tid & 63;
  if (ln == 0) { rs[wv] = ps; rq[wv] = pq; }
  __syncthreads();
  if (tid == 0) {
    float S = rs[0] + rs[1] + rs[2] + rs[3];
    float Q = rq[0] + rq[1] + rq[2] + rq[3];
    float cnt = fmaxf((float)(e - b) * (float)DD, 1.0f);
    float mu  = S / cnt;
    float var = fmaxf(Q / cnt - mu * mu, 0.0f);
    gmu[g]   = mu;
    grstd[g] = rsqrtf(var + 1e-5f);
  }
}

// ---------------- graph-LN normalize, f16 in / f16 out ----------------
__global__ __launch_bounds__(256) void k_norm(__half* __restrict__ x, const int* __restrict__ batch,
                                              const float* __restrict__ gmu, const float* __restrict__ grstd,
                                              const float* __restrict__ lnw, const float* __restrict__ lnb) {
  for (int i8 = blockIdx.x * 256 + threadIdx.x; i8 < NN * DD / 8; i8 += gridDim.x * 256) {
    int i = i8 * 8;
    int n = i >> 9, d = i & 511;
    int g = batch[n];
    float mu = gmu[g], rs = grstd[g];
    uint4 raw = *(uint4*)(x + i);
    __half2* hp = (__half2*)&raw;
    float4 w0 = *(const float4*)(lnw + d);
    float4 w1 = *(const float4*)(lnw + d + 4);
    float4 b0 = *(const float4*)(lnb + d);
    float4 b1 = *(const float4*)(lnb + d + 4);
    float wv[8] = {w0.x,w0.y,w0.z,w0.w,w1.x,w1.y,w1.z,w1.w};
    float bv[8] = {b0.x,b0.y,b0.z,b0.w,b1.x,b1.y,b1.z,b1.w};
#pragma unroll
    for (int j = 0; j < 4; ++j) {
      float2 f = __half22float2(hp[j]);
      f.x = (f.x - mu) * rs * wv[2*j]   + bv[2*j];
      f.y = (f.y - mu) * rs * wv[2*j+1] + bv[2*j+1];
      hp[j] = __floats2half2_rn(f.x, f.y);
    }
    *(uint4*)(x + i) = raw;
  }
}

// ---------------- pooling stage 1: per-(graph, slice) partials ----------------
__global__ __launch_bounds__(256) void k_poolp(const __half* __restrict__ x, const int* __restrict__ batch,
                                               float* __restrict__ pps, float* __restrict__ ppm) {
  int g = blockIdx.x, z = blockIdx.y, tid = threadIdx.x;
  __shared__ int sb, se;
  if (tid == 0) { sb = lowb(batch, NN, g); se = lowb(batch, NN, g + 1); }
  __syncthreads();
  int b = sb, e = se, cnt = e - b;
  int len = (cnt + 7) >> 3;
  int nb = b + z * len, ne = min(nb + len, e);
  float s0 = 0.f, s1 = 0.f, m0 = -INFINITY, m1 = -INFINITY;
  for (int n = nb; n < ne; ++n) {
    float v0 = __half2float(x[(size_t)n * DD + tid]);
    float v1 = __half2float(x[(size_t)n * DD + tid + 256]);
    s0 += v0; s1 += v1;
    m0 = fmaxf(m0, v0); m1 = fmaxf(m1, v1);
  }
  size_t o = ((size_t)g * 8 + z) * 512;
  pps[o + tid]       = s0;
  pps[o + tid + 256] = s1;
  ppm[o + tid]       = m0;
  ppm[o + tid + 256] = m1;
}

// ---------------- pooling stage 2: combine 8 slices -> f16 [G][1024] ----------------
__global__ __launch_bounds__(256) void k_poolc(const float* __restrict__ pps, const float* __restrict__ ppm,
                                               const int* __restrict__ batch, __half* __restrict__ pool16) {
  int g = blockIdx.x, tid = threadIdx.x;
  __shared__ int sb, se;
  if (tid == 0) { sb = lowb(batch, NN, g); se = lowb(batch, NN, g + 1); }
  __syncthreads();
  int cnt = se - sb;
  float s0 = 0.f, s1 = 0.f, m0 = -INFINITY, m1 = -INFINITY;
#pragma unroll
  for (int z = 0; z < 8; ++z) {
    size_t o = ((size_t)g * 8 + z) * 512;
    s0 += pps[o + tid];
    s1 += pps[o + tid + 256];
    m0 = fmaxf(m0, ppm[o + tid]);
    m1 = fmaxf(m1, ppm[o + tid + 256]);
  }
  float inv = 1.0f / (float)(cnt > 0 ? cnt : 1);
  pool16[(size_t)g * 1024 + tid]             = __float2half_rn(s0 * inv);
  pool16[(size_t)g * 1024 + tid + 256]       = __float2half_rn(s1 * inv);
  pool16[(size_t)g * 1024 + 512 + tid]       = __float2half_rn((cnt > 0) ? m0 : 0.f);
  pool16[(size_t)g * 1024 + 512 + tid + 256] = __float2half_rn((cnt > 0) ? m1 : 0.f);
}

// ---------------- launcher ----------------
extern "C" void kernel_launch(void* const* d_in, const int* in_sizes, int n_in,
                              void* d_out, int out_size, void* d_ws, size_t ws_size,
                              hipStream_t stream) {
  const int*   node_ids = (const int*)d_in[0];
  const int*   ei       = (const int*)d_in[1];
  const int*   batch    = (const int*)d_in[2];
  const float* emb      = (const float*)d_in[3];
  const float* W[4]  = {(const float*)d_in[4],  (const float*)d_in[10], (const float*)d_in[16], (const float*)d_in[22]};
  const float* AS[4] = {(const float*)d_in[5],  (const float*)d_in[11], (const float*)d_in[17], (const float*)d_in[23]};
  const float* AD[4] = {(const float*)d_in[6],  (const float*)d_in[12], (const float*)d_in[18], (const float*)d_in[24]};
  const float* BV[4] = {(const float*)d_in[7],  (const float*)d_in[13], (const float*)d_in[19], (const float*)d_in[25]};
  const float* LW[4] = {(const float*)d_in[8],  (const float*)d_in[14], (const float*)d_in[20], (const float*)d_in[26]};
  const float* LB[4] = {(const float*)d_in[9],  (const float*)d_in[15], (const float*)d_in[21], (const float*)d_in[27]};
  const float* res_w0 = (const float*)d_in[28];
  const float* p1w    = (const float*)d_in[29];
  const float* p1b    = (const float*)d_in[30];
  const float* p2w    = (const float*)d_in[31];
  const float* p2b    = (const float*)d_in[32];
  float* out = (float*)d_out;

  char* ws = (char*)d_ws;
  size_t pos = 0;
  auto alloc = [&](size_t bytes) -> char* {
    char* p = ws + pos;
    pos = (pos + bytes + 255) & ~size_t(255);
    return p;
  };
  __half* xr16  = (__half*)alloc((size_t)NN * DD * 2);   // unified residual / GEMM-A / pool input
  __half* xp16  = (__half*)alloc((size_t)NN * DD * 2);
  __half* x0f   = (__half*)alloc((size_t)NN * DEE * 2);
  float*  ssrc  = (float*)alloc((size_t)NN * 4 * 4);
  float*  sdst  = (float*)alloc((size_t)NN * 4 * 4);
  float*  sspS  = (float*)alloc((size_t)2 * NN * 4 * 4);
  float*  sspD  = (float*)alloc((size_t)2 * NN * 4 * 4);
  int*    coff  = (int*)alloc((size_t)(NN + 1) * 4);
  int*    ccur  = (int*)alloc((size_t)NN * 4);
  int*    csrc  = (int*)alloc((size_t)ET * 4);
  unsigned* ewk = (unsigned*)alloc((size_t)ET * 4 * 4);  // 4 head planes of packed {src,f16 alpha}
  float*  psq   = (float*)alloc((size_t)NN * 16 * 4);
  float*  gmu   = (float*)alloc((size_t)GG * 4 * 2);
  float*  grstd = gmu + GG;
  // transposed f16 weights
  __half* w0t = (__half*)alloc((size_t)DEE * DD * 2);
  __half* rwt = (__half*)alloc((size_t)DEE * DD * 2);
  __half* wt[4] = {w0t, nullptr, nullptr, nullptr};
  for (int i = 1; i < 4; ++i) wt[i] = (__half*)alloc((size_t)DD * DD * 2);
  __half* p1t = (__half*)alloc((size_t)1024 * 1024 * 2);
  __half* p2t = (__half*)alloc((size_t)OUTD * 1024 * 2);
  __half* pool16 = (__half*)alloc((size_t)GG * 1024 * 2);
  __half* h1_16  = (__half*)alloc((size_t)GG * 1024 * 2);
  float*  pps    = (float*)alloc((size_t)GG * 8 * 512 * 4);  // 2 MB
  float*  ppm    = (float*)alloc((size_t)GG * 8 * 512 * 4);  // 2 MB
  float*  part1  = (float*)alloc((size_t)8 * GG * 1024 * 4); // 4 MB
  float*  part2  = (float*)alloc((size_t)8 * GG * OUTD * 4); // 1 MB
  (void)ws_size; (void)in_sizes; (void)n_in; (void)out_size;

  // ---- CSR + weight prep ----
  hipMemsetAsync(ccur, 0, (size_t)NN * 4, stream);
  k_embf16<<<1250, 256, 0, stream>>>(node_ids, emb, x0f);
  k_count<<<1024, 256, 0, stream>>>(ei, ccur);
  k_scan<<<1, 1024, 0, stream>>>(ccur, coff);
  hipMemsetAsync(ccur, 0, (size_t)NN * 4, stream);
  k_scatter<<<1024, 256, 0, stream>>>(ei, coff, ccur, csrc);
  k_wT16<<<dim3(16, 2),  256, 0, stream>>>(W[0],   w0t, DEE, DD);
  k_wT16<<<dim3(16, 2),  256, 0, stream>>>(res_w0, rwt, DEE, DD);
  for (int i = 1; i < 4; ++i)
    k_wT16<<<dim3(16, 16), 256, 0, stream>>>(W[i], wt[i], DD, DD);
  k_wT16<<<dim3(32, 32), 256, 0, stream>>>(p1w, p1t, 1024, 1024);
  k_wT16<<<dim3(8, 32),  256, 0, stream>>>(p2w, p2t, 1024, OUTD);

  // ---- L0 projections (xp GEMM carries fused attention dots via wc-partials) ----
  k_mfma3<1><<<dim3(4, 157), 256, 0, stream>>>(x0f, w0t, xp16, NN, DEE, DD,
                                               AS[0], AD[0], sspS, sspD);
  k_mfma3<0><<<dim3(4, 157), 256, 0, stream>>>(x0f, rwt, xr16, NN, DEE, DD,
                                               nullptr, nullptr, nullptr, nullptr);
  k_scomb<<<(NN * 4 + 255) / 256, 256, 0, stream>>>(sspS, sspD, ssrc, sdst);

  // ---- 4 GAT layers ----
  for (int L = 0; L < 4; ++L) {
    k_eweight<<<NN / 4, 256, 0, stream>>>(ssrc, sdst, coff, csrc, ewk);
    k_aggc<<<NN * 2, 256, 0, stream>>>(xp16, ewk, coff, BV[L], xr16, psq);
    k_stats2<<<GG, 256, 0, stream>>>(psq, batch, gmu, grstd);
    k_norm<<<2048, 256, 0, stream>>>(xr16, batch, gmu, grstd, LW[L], LB[L]);
    if (L < 3) {
      k_mfma3<1><<<dim3(4, 157), 256, 0, stream>>>(xr16, wt[L + 1], xp16, NN, DD, DD,
                                                   AS[L + 1], AD[L + 1], sspS, sspD);
      k_scomb<<<(NN * 4 + 255) / 256, 256, 0, stream>>>(sspS, sspD, ssrc, sdst);
    }
  }

  // ---- pool (2-stage) + MLP head (split-K) + fused finalize/normalize ----
  k_poolp<<<dim3(GG, 8), 256, 0, stream>>>(xr16, batch, pps, ppm);
  k_poolc<<<GG, 256, 0, stream>>>(pps, ppm, batch, pool16);
  k_mfmaK<<<dim3(8, 1, 8), 256, 0, stream>>>(pool16, p1t, part1, GG, 1024, 1024, 128);
  k_fin_gelu<<<512, 256, 0, stream>>>(part1, p1b, h1_16);
  k_mfmaK<<<dim3(2, 1, 8), 256, 0, stream>>>(h1_16, p2t, part2, GG, 1024, OUTD, 128);
  k_fin_l2<<<GG, 256, 0, stream>>>(part2, p2b, out);
}